// Round 2
// baseline (328.943 us; speedup 1.0000x reference)
//
#include <hip/hip_runtime.h>

// AdaptiveSparsityAttention on MI355X (gfx950).
// f32 in/out, internal bf16 MFMA for attention; mask logits in pure f32 via
// algebraic fusion:  a = x @ (0.5*(Wq[:,:256]+Wq[:,256:]) @ W1[:256])  (exact
// linearity of head-mean), so the discontinuous mask threshold sees f32-grade
// logits and bf16 GEMM error cannot flip mask bits.
//
// Pipeline (all on `stream`):
//  k_xconv:  x (f32) -> xb (bf16)
//  k_trans:  Wq,Wk,Wv,Wo (f32 [k][n]) -> WT (bf16 [n][k])      (x4 launches)
//  k_qkv:    q/k/v = xb @ W  (MFMA) -> qb,kb (bf16), vT (bf16 transposed)
//  k_eff:    Aeff = Wqm @ W1[:256], Ceff = Wkm @ W1[256:]  (f32)
//  k_ac:     a = x @ Aeff, c = x @ Ceff  (f32 VALU)
//  k_mask:   maskb[b][i][j] = (sum_h relu(a_i+c_j+b1)*W2 + b2) > 0
//  k_scores: scores = (q@k^T)/16, masked -> -1e9  (MFMA, f32 out)
//  k_softmax: row softmax -> P (bf16)
//  k_pv:     ao = P @ v   (MFMA, bf16 out)
//  k_out:    out = ao @ Wo + bo  (MFMA, f32 out)

typedef unsigned short u16t;
typedef __bf16 bf16x8 __attribute__((ext_vector_type(8)));
typedef float f32x4 __attribute__((ext_vector_type(4)));

#define B_SZ 2
#define S_SZ 1024
#define D_SZ 512
#define DH 256
#define HH 128   // hidden dim of sparsity predictor

static __device__ __forceinline__ u16t f2b(float f) {
    unsigned int u = __builtin_bit_cast(unsigned int, f);
    u += 0x7FFFu + ((u >> 16) & 1u);
    return (u16t)(u >> 16);
}

static __device__ __forceinline__ f32x4 mfma16(bf16x8 a, bf16x8 b, f32x4 c) {
    return __builtin_amdgcn_mfma_f32_16x16x32_bf16(a, b, c, 0, 0, 0);
}

// ---------------------------------------------------------------- small prep
__global__ void k_xconv(const float* __restrict__ x, u16t* __restrict__ xb) {
    int idx = (blockIdx.x * 256 + threadIdx.x) * 4;
    float4 v = *(const float4*)(x + idx);
    u16t* o = xb + idx;
    o[0] = f2b(v.x); o[1] = f2b(v.y); o[2] = f2b(v.z); o[3] = f2b(v.w);
}

// W f32 [512][512] row-major [k][n]  ->  WT bf16 [n][k]
__global__ void k_trans(const float* __restrict__ W, u16t* __restrict__ WT) {
    __shared__ float tile[32][33];
    int n0 = blockIdx.x * 32, k0 = blockIdx.y * 32;
    int r = threadIdx.x >> 3, c4 = (threadIdx.x & 7) * 4;
    float4 v = *(const float4*)(W + (size_t)(k0 + r) * D_SZ + n0 + c4);
    tile[r][c4] = v.x; tile[r][c4 + 1] = v.y; tile[r][c4 + 2] = v.z; tile[r][c4 + 3] = v.w;
    __syncthreads();
    u16t o[4];
    o[0] = f2b(tile[c4][r]); o[1] = f2b(tile[c4 + 1][r]);
    o[2] = f2b(tile[c4 + 2][r]); o[3] = f2b(tile[c4 + 3][r]);
    *(ushort4*)(WT + (size_t)(n0 + r) * D_SZ + k0 + c4) = *(ushort4*)o;
}

// ------------------------------------------------------------- GEMM mainloop
// C[BM=128][BN=64] per block (256 thr, 4 waves; wave w owns rows w*32..+32).
// A: [M][K] k-contig (pre-offset to row m0), B: [N][K] k-contig (pre-offset to n0).
#define KP 72  // padded LDS row stride (bf16 elems): +8 kills bank conflicts, keeps 16B align

static __device__ __forceinline__ void gemm_mainloop(
    const u16t* __restrict__ A, int lda, const u16t* __restrict__ B, int ldb,
    int K, int tid, u16t* Als, u16t* Bls, f32x4 acc[2][4])
{
    const int w = tid >> 6, lane = tid & 63;
    const int lr = lane & 15, kg = lane >> 4;
    for (int k0 = 0; k0 < K; k0 += 64) {
        if (k0) __syncthreads();
        {
            int c = tid & 7, r0 = tid >> 3;
#pragma unroll
            for (int p = 0; p < 4; ++p) {
                int r = r0 + p * 32;
                *(uint4*)(&Als[r * KP + c * 8]) = *(const uint4*)(&A[(size_t)r * lda + k0 + c * 8]);
            }
#pragma unroll
            for (int p = 0; p < 2; ++p) {
                int r = r0 + p * 32;
                *(uint4*)(&Bls[r * KP + c * 8]) = *(const uint4*)(&B[(size_t)r * ldb + k0 + c * 8]);
            }
        }
        __syncthreads();
#pragma unroll
        for (int kk = 0; kk < 2; ++kk) {
            bf16x8 af[2], bfr[4];
#pragma unroll
            for (int fi = 0; fi < 2; ++fi)
                af[fi] = *(const bf16x8*)(&Als[(w * 32 + fi * 16 + lr) * KP + kk * 32 + kg * 8]);
#pragma unroll
            for (int fj = 0; fj < 4; ++fj)
                bfr[fj] = *(const bf16x8*)(&Bls[(fj * 16 + lr) * KP + kk * 32 + kg * 8]);
#pragma unroll
            for (int fi = 0; fi < 2; ++fi)
#pragma unroll
                for (int fj = 0; fj < 4; ++fj)
                    acc[fi][fj] = mfma16(af[fi], bfr[fj], acc[fi][fj]);
        }
    }
}

// C-frag element (fi,fj,rr): row = m0+w*32+fi*16+kg*4+rr, col = n0+fj*16+lr  [m89-verified]

// ------------------------------------------------------------------ K1: QKV
__global__ __launch_bounds__(256) void k_qkv(
    const u16t* __restrict__ xb, const u16t* __restrict__ WT,
    u16t* __restrict__ qb, u16t* __restrict__ kb, u16t* __restrict__ vT)
{
    __shared__ u16t Als[128 * KP];
    __shared__ u16t Bls[64 * KP];
    int z = blockIdx.z;
    int m0 = blockIdx.y * 128, n0 = blockIdx.x * 64;
    const u16t* A = xb + (size_t)m0 * D_SZ;
    const u16t* Bt = WT + (size_t)z * D_SZ * D_SZ + (size_t)n0 * D_SZ;
    f32x4 acc[2][4] = {};
    gemm_mainloop(A, D_SZ, Bt, D_SZ, D_SZ, threadIdx.x, Als, Bls, acc);
    int w = threadIdx.x >> 6, lane = threadIdx.x & 63, lr = lane & 15, kg = lane >> 4;
#pragma unroll
    for (int fi = 0; fi < 2; ++fi)
#pragma unroll
        for (int fj = 0; fj < 4; ++fj)
#pragma unroll
            for (int rr = 0; rr < 4; ++rr) {
                int row = m0 + w * 32 + fi * 16 + kg * 4 + rr;
                int col = n0 + fj * 16 + lr;
                u16t v = f2b(acc[fi][fj][rr]);
                if (z == 0) {
                    qb[(size_t)row * D_SZ + col] = v;
                } else if (z == 1) {
                    kb[(size_t)row * D_SZ + col] = v;
                } else {
                    int b = row >> 10, s = row & 1023;
                    vT[(((size_t)b * D_SZ + col) << 10) + s] = v;
                }
            }
}

// ------------------------------------- K2a: effective mask matrices (f32)
// Aeff[k][h] = sum_d 0.5*(Wq[k][d]+Wq[k][d+256]) * W1[d][h]      (d<256)
// Ceff[k][h] = sum_d 0.5*(Wk[k][d]+Wk[k][d+256]) * W1[256+d][h]
__global__ void k_eff(const float* __restrict__ Wq, const float* __restrict__ Wk,
                      const float* __restrict__ W1,
                      float* __restrict__ Aeff, float* __restrict__ Ceff)
{
    int k = blockIdx.x;      // 512
    int t = threadIdx.x;     // 128
    const float* W = blockIdx.y ? Wk : Wq;
    const float* W1h = W1 + (blockIdx.y ? (size_t)DH * HH : 0);
    __shared__ float wm[256];
    const float* wr = W + (size_t)k * D_SZ;
    for (int d = t; d < 256; d += 128) wm[d] = 0.5f * (wr[d] + wr[d + DH]);
    __syncthreads();
    float s = 0.f;
    for (int d = 0; d < 256; ++d) s += wm[d] * W1h[(size_t)d * HH + t];
    float* dst = blockIdx.y ? Ceff : Aeff;
    dst[(size_t)k * HH + t] = s;
}

// ------------------------------------- K2b: a = x@Aeff, c = x@Ceff (f32 VALU)
__global__ __launch_bounds__(256) void k_ac(
    const float* __restrict__ x, const float* __restrict__ Aeff,
    const float* __restrict__ Ceff, float* __restrict__ a, float* __restrict__ cc)
{
    int r0 = blockIdx.x * 16;   // 128 blocks
    int t = threadIdx.x;
    int col = t & 127, rg = t >> 7;  // rg 0/1 -> rows rg*8..+8
    __shared__ float xs[16][512];
    for (int i = t; i < 16 * 128; i += 256) {
        int rr = i >> 7, d4 = (i & 127) * 4;
        *(float4*)&xs[rr][d4] = *(const float4*)(x + (size_t)(r0 + rr) * D_SZ + d4);
    }
    __syncthreads();
    float sa[8] = {}, sc[8] = {};
    for (int d = 0; d < 512; ++d) {
        float av = Aeff[(size_t)d * HH + col];
        float cv = Ceff[(size_t)d * HH + col];
#pragma unroll
        for (int rr = 0; rr < 8; ++rr) {
            float xv = xs[rg * 8 + rr][d];   // wave-uniform addr -> LDS broadcast
            sa[rr] += xv * av;
            sc[rr] += xv * cv;
        }
    }
#pragma unroll
    for (int rr = 0; rr < 8; ++rr) {
        a[(size_t)(r0 + rg * 8 + rr) * HH + col] = sa[rr];
        cc[(size_t)(r0 + rg * 8 + rr) * HH + col] = sc[rr];
    }
}

// ------------------------------------------------------------- K3: mask bits
__global__ __launch_bounds__(256) void k_mask(
    const float* __restrict__ a, const float* __restrict__ c,
    const float* __restrict__ b1, const float* __restrict__ W2,
    const float* __restrict__ b2, unsigned char* __restrict__ maskb)
{
    int b = blockIdx.y, i0 = blockIdx.x * 16;
    int t = threadIdx.x;
    __shared__ __align__(16) float al[16][132];
    __shared__ __align__(16) float b1s[128];
    __shared__ __align__(16) float w2s[128];
    if (t < 128) { b1s[t] = b1[t]; w2s[t] = W2[t]; }
    {
        int ii = t >> 4, h0 = (t & 15) * 8;
        const float* src = a + ((size_t)(b * S_SZ + i0 + ii)) * HH + h0;
        float4 v0 = *(const float4*)src;
        float4 v1 = *(const float4*)(src + 4);
        *(float4*)&al[ii][h0] = v0;
        *(float4*)&al[ii][h0 + 4] = v1;
    }
    __syncthreads();
    float fb2 = b2[0];
    int i = t & 15, jg = t >> 4;
    const float* arow = al[i];
    const float* cb = c + ((size_t)b << 10) * HH;
    unsigned char* mrow = maskb + ((size_t)b << 20) + ((size_t)(i0 + i) << 10);
    for (int jj = 0; jj < 64; ++jj) {
        int j = jj * 16 + jg;
        const float* cj = cb + (size_t)j * HH;
        float accv = 0.f;
#pragma unroll 8
        for (int h4 = 0; h4 < 32; ++h4) {
            float4 cv = ((const float4*)cj)[h4];
            float4 av = *(const float4*)&arow[h4 * 4];
            float4 bv = ((const float4*)b1s)[h4];
            float4 wv = ((const float4*)w2s)[h4];
            accv += fmaxf(av.x + cv.x + bv.x, 0.f) * wv.x;
            accv += fmaxf(av.y + cv.y + bv.y, 0.f) * wv.y;
            accv += fmaxf(av.z + cv.z + bv.z, 0.f) * wv.z;
            accv += fmaxf(av.w + cv.w + bv.w, 0.f) * wv.w;
        }
        mrow[j] = (accv + fb2) > 0.f ? 1 : 0;
    }
}

// ---------------------------------------------------- K4: scores (masked QK^T)
__global__ __launch_bounds__(256) void k_scores(
    const u16t* __restrict__ qb, const u16t* __restrict__ kb,
    const unsigned char* __restrict__ maskb, float* __restrict__ scores)
{
    __shared__ u16t Als[128 * KP];
    __shared__ u16t Bls[64 * KP];
    int bh = blockIdx.z, b = bh >> 1, h = bh & 1;
    int m0 = blockIdx.y * 128, n0 = blockIdx.x * 64;
    const u16t* A = qb + (size_t)b * S_SZ * D_SZ + (size_t)m0 * D_SZ + h * DH;
    const u16t* Bt = kb + (size_t)b * S_SZ * D_SZ + (size_t)n0 * D_SZ + h * DH;
    f32x4 acc[2][4] = {};
    gemm_mainloop(A, D_SZ, Bt, D_SZ, DH, threadIdx.x, Als, Bls, acc);
    int w = threadIdx.x >> 6, lane = threadIdx.x & 63, lr = lane & 15, kg = lane >> 4;
#pragma unroll
    for (int fi = 0; fi < 2; ++fi)
#pragma unroll
        for (int fj = 0; fj < 4; ++fj)
#pragma unroll
            for (int rr = 0; rr < 4; ++rr) {
                int i = m0 + w * 32 + fi * 16 + kg * 4 + rr;
                int j = n0 + fj * 16 + lr;
                float v = acc[fi][fj][rr] * 0.0625f;  // 1/sqrt(256)
                bool msk = maskb[((size_t)b << 20) + ((size_t)i << 10) + j] != 0;
                scores[((size_t)bh << 20) + ((size_t)i << 10) + j] = msk ? v : -1e9f;
            }
}

// --------------------------------------------------------------- K5: softmax
__global__ void k_softmax(const float* __restrict__ scores, u16t* __restrict__ P) {
    int row = blockIdx.x;  // (b*2+h)*1024 + i
    int t = threadIdx.x;
    const float* src = scores + ((size_t)row << 10);
    float4 v = ((const float4*)src)[t];
    float m = fmaxf(fmaxf(v.x, v.y), fmaxf(v.z, v.w));
    for (int o = 32; o; o >>= 1) m = fmaxf(m, __shfl_xor(m, o));
    __shared__ float redm[4];
    __shared__ float reds[4];
    int w = t >> 6;
    if ((t & 63) == 0) redm[w] = m;
    __syncthreads();
    m = fmaxf(fmaxf(redm[0], redm[1]), fmaxf(redm[2], redm[3]));
    float e0 = expf(v.x - m), e1 = expf(v.y - m), e2 = expf(v.z - m), e3 = expf(v.w - m);
    float s = e0 + e1 + e2 + e3;
    for (int o = 32; o; o >>= 1) s += __shfl_xor(s, o);
    if ((t & 63) == 0) reds[w] = s;
    __syncthreads();
    s = reds[0] + reds[1] + reds[2] + reds[3];
    float inv = 1.0f / s;
    u16t o4[4] = { f2b(e0 * inv), f2b(e1 * inv), f2b(e2 * inv), f2b(e3 * inv) };
    *(ushort4*)(P + ((size_t)row << 10) + t * 4) = *(ushort4*)o4;
}

// -------------------------------------------------------------------- K6: PV
__global__ __launch_bounds__(256) void k_pv(
    const u16t* __restrict__ P, const u16t* __restrict__ vT, u16t* __restrict__ ao)
{
    __shared__ u16t Als[128 * KP];
    __shared__ u16t Bls[64 * KP];
    int bh = blockIdx.z, b = bh >> 1, h = bh & 1;
    int m0 = blockIdx.y * 128, n0 = blockIdx.x * 64;
    const u16t* A = P + ((size_t)bh << 20) + (size_t)m0 * S_SZ;
    const u16t* Bt = vT + ((size_t)(b * D_SZ + h * DH + n0)) * S_SZ;
    f32x4 acc[2][4] = {};
    gemm_mainloop(A, S_SZ, Bt, S_SZ, S_SZ, threadIdx.x, Als, Bls, acc);
    int w = threadIdx.x >> 6, lane = threadIdx.x & 63, lr = lane & 15, kg = lane >> 4;
#pragma unroll
    for (int fi = 0; fi < 2; ++fi)
#pragma unroll
        for (int fj = 0; fj < 4; ++fj)
#pragma unroll
            for (int rr = 0; rr < 4; ++rr) {
                int i = m0 + w * 32 + fi * 16 + kg * 4 + rr;
                int d = n0 + fj * 16 + lr;  // within head
                ao[((size_t)(b * S_SZ + i)) * D_SZ + h * DH + d] = f2b(acc[fi][fj][rr]);
            }
}

// ------------------------------------------------------------ K7: out = ao@Wo+bo
__global__ __launch_bounds__(256) void k_out(
    const u16t* __restrict__ ao, const u16t* __restrict__ WoT,
    const float* __restrict__ bo, float* __restrict__ out)
{
    __shared__ u16t Als[128 * KP];
    __shared__ u16t Bls[64 * KP];
    int m0 = blockIdx.y * 128, n0 = blockIdx.x * 64;
    const u16t* A = ao + (size_t)m0 * D_SZ;
    const u16t* Bt = WoT + (size_t)n0 * D_SZ;
    f32x4 acc[2][4] = {};
    gemm_mainloop(A, D_SZ, Bt, D_SZ, D_SZ, threadIdx.x, Als, Bls, acc);
    int w = threadIdx.x >> 6, lane = threadIdx.x & 63, lr = lane & 15, kg = lane >> 4;
#pragma unroll
    for (int fi = 0; fi < 2; ++fi)
#pragma unroll
        for (int fj = 0; fj < 4; ++fj)
#pragma unroll
            for (int rr = 0; rr < 4; ++rr) {
                int row = m0 + w * 32 + fi * 16 + kg * 4 + rr;
                int col = n0 + fj * 16 + lr;
                out[(size_t)row * D_SZ + col] = acc[fi][fj][rr] + bo[col];
            }
}

// ---------------------------------------------------------------------- host
extern "C" void kernel_launch(void* const* d_in, const int* in_sizes, int n_in,
                              void* d_out, int out_size, void* d_ws, size_t ws_size,
                              hipStream_t stream)
{
    const float* x  = (const float*)d_in[0];
    const float* Wmat[4] = { (const float*)d_in[1], (const float*)d_in[2],
                             (const float*)d_in[3], (const float*)d_in[4] };
    const float* bo = (const float*)d_in[5];
    const float* W1 = (const float*)d_in[6];
    const float* b1 = (const float*)d_in[7];
    const float* W2 = (const float*)d_in[8];
    const float* b2 = (const float*)d_in[9];
    float* out = (float*)d_out;

    // workspace carve (all 256B-aligned)
    char* ws = (char*)d_ws;
    size_t off = 0;
    auto carve = [&](size_t bytes) { void* p = ws + off; off += (bytes + 255) & ~(size_t)255; return p; };
    u16t* xb   = (u16t*)carve((size_t)2048 * 512 * 2);
    u16t* WT   = (u16t*)carve((size_t)4 * 512 * 512 * 2);
    u16t* qb   = (u16t*)carve((size_t)2048 * 512 * 2);
    u16t* kb   = (u16t*)carve((size_t)2048 * 512 * 2);
    u16t* vT   = (u16t*)carve((size_t)2 * 512 * 1024 * 2);
    float* Aeff = (float*)carve((size_t)512 * 128 * 4);
    float* Ceff = (float*)carve((size_t)512 * 128 * 4);
    float* a   = (float*)carve((size_t)2048 * 128 * 4);
    float* c   = (float*)carve((size_t)2048 * 128 * 4);
    unsigned char* maskb = (unsigned char*)carve((size_t)2 * 1024 * 1024);
    float* scores = (float*)carve((size_t)4 * 1024 * 1024 * 4);
    u16t* P    = (u16t*)carve((size_t)4 * 1024 * 1024 * 2);
    u16t* ao   = (u16t*)carve((size_t)2048 * 512 * 2);
    (void)ws_size;

    k_xconv<<<dim3(1024), dim3(256), 0, stream>>>(x, xb);
    for (int z = 0; z < 4; ++z)
        k_trans<<<dim3(16, 16), dim3(256), 0, stream>>>(Wmat[z], WT + (size_t)z * 512 * 512);
    k_qkv<<<dim3(8, 16, 3), dim3(256), 0, stream>>>(xb, WT, qb, kb, vT);
    k_eff<<<dim3(512, 2), dim3(128), 0, stream>>>(Wmat[0], Wmat[1], W1, Aeff, Ceff);
    k_ac<<<dim3(128), dim3(256), 0, stream>>>(x, Aeff, Ceff, a, c);
    k_mask<<<dim3(64, 2), dim3(256), 0, stream>>>(a, c, b1, W2, b2, maskb);
    k_scores<<<dim3(16, 8, 4), dim3(256), 0, stream>>>(qb, kb, maskb, scores);
    k_softmax<<<dim3(4096), dim3(256), 0, stream>>>(scores, P);
    k_pv<<<dim3(4, 8, 4), dim3(256), 0, stream>>>(P, vT, ao);
    k_out<<<dim3(8, 16), dim3(256), 0, stream>>>(ao, WT + (size_t)3 * 512 * 512, bo, out);
}

// Round 3
// 134.383 us; speedup vs baseline: 2.4478x; 2.4478x over previous
//
#include <hip/hip_runtime.h>

// AdaptiveSparsityAttention on MI355X (gfx950).
// f32 in/out, internal bf16 MFMA for attention; mask logits in pure f32 via
// algebraic fusion:  a = x @ (0.5*(Wq[:,:256]+Wq[:,256:]) @ W1[:256]) + b1.
//
// R3: k_mask re-tiled (512 blocks, 4x4 reg blocking)  [was 169us @ 5.7% occ]
//     k_ac -> tiled f32 GEMM x@Beff (256 blocks)      [was serial, 0.5 blk/CU]
//     k_pv/k_out -> BN=32 mainloop (256 blocks each)  [were 128 blocks]

typedef unsigned short u16t;
typedef __bf16 bf16x8 __attribute__((ext_vector_type(8)));
typedef float f32x4 __attribute__((ext_vector_type(4)));

#define B_SZ 2
#define S_SZ 1024
#define D_SZ 512
#define DH 256
#define HH 128   // hidden dim of sparsity predictor

static __device__ __forceinline__ u16t f2b(float f) {
    unsigned int u = __builtin_bit_cast(unsigned int, f);
    u += 0x7FFFu + ((u >> 16) & 1u);
    return (u16t)(u >> 16);
}

static __device__ __forceinline__ f32x4 mfma16(bf16x8 a, bf16x8 b, f32x4 c) {
    return __builtin_amdgcn_mfma_f32_16x16x32_bf16(a, b, c, 0, 0, 0);
}

// ---------------------------------------------------------------- small prep
__global__ void k_xconv(const float* __restrict__ x, u16t* __restrict__ xb) {
    int idx = (blockIdx.x * 256 + threadIdx.x) * 4;
    float4 v = *(const float4*)(x + idx);
    u16t* o = xb + idx;
    o[0] = f2b(v.x); o[1] = f2b(v.y); o[2] = f2b(v.z); o[3] = f2b(v.w);
}

// W f32 [512][512] row-major [k][n]  ->  WT bf16 [n][k]
__global__ void k_trans(const float* __restrict__ W, u16t* __restrict__ WT) {
    __shared__ float tile[32][33];
    int n0 = blockIdx.x * 32, k0 = blockIdx.y * 32;
    int r = threadIdx.x >> 3, c4 = (threadIdx.x & 7) * 4;
    float4 v = *(const float4*)(W + (size_t)(k0 + r) * D_SZ + n0 + c4);
    tile[r][c4] = v.x; tile[r][c4 + 1] = v.y; tile[r][c4 + 2] = v.z; tile[r][c4 + 3] = v.w;
    __syncthreads();
    u16t o[4];
    o[0] = f2b(tile[c4][r]); o[1] = f2b(tile[c4 + 1][r]);
    o[2] = f2b(tile[c4 + 2][r]); o[3] = f2b(tile[c4 + 3][r]);
    *(ushort4*)(WT + (size_t)(n0 + r) * D_SZ + k0 + c4) = *(ushort4*)o;
}

// ------------------------------------------------------------- GEMM mainloop
// C[BM=128][BN=NF*16] per block (256 thr, 4 waves; wave w owns rows w*32..+32).
// A: [M][K] k-contig (pre-offset to row m0), B: [N][K] k-contig (pre-offset to n0).
#define KP 72  // padded LDS row stride (bf16 elems)

template<int NF>
static __device__ __forceinline__ void gemm_mainloop(
    const u16t* __restrict__ A, int lda, const u16t* __restrict__ B, int ldb,
    int K, int tid, u16t* Als, u16t* Bls, f32x4 acc[2][NF])
{
    const int w = tid >> 6, lane = tid & 63;
    const int lr = lane & 15, kg = lane >> 4;
    for (int k0 = 0; k0 < K; k0 += 64) {
        if (k0) __syncthreads();
        {
            int c = tid & 7, r0 = tid >> 3;
#pragma unroll
            for (int p = 0; p < 4; ++p) {
                int r = r0 + p * 32;
                *(uint4*)(&Als[r * KP + c * 8]) = *(const uint4*)(&A[(size_t)r * lda + k0 + c * 8]);
            }
#pragma unroll
            for (int p = 0; p < NF / 2; ++p) {
                int r = r0 + p * 32;
                *(uint4*)(&Bls[r * KP + c * 8]) = *(const uint4*)(&B[(size_t)r * ldb + k0 + c * 8]);
            }
        }
        __syncthreads();
#pragma unroll
        for (int kk = 0; kk < 2; ++kk) {
            bf16x8 af[2], bfr[NF];
#pragma unroll
            for (int fi = 0; fi < 2; ++fi)
                af[fi] = *(const bf16x8*)(&Als[(w * 32 + fi * 16 + lr) * KP + kk * 32 + kg * 8]);
#pragma unroll
            for (int fj = 0; fj < NF; ++fj)
                bfr[fj] = *(const bf16x8*)(&Bls[(fj * 16 + lr) * KP + kk * 32 + kg * 8]);
#pragma unroll
            for (int fi = 0; fi < 2; ++fi)
#pragma unroll
                for (int fj = 0; fj < NF; ++fj)
                    acc[fi][fj] = mfma16(af[fi], bfr[fj], acc[fi][fj]);
        }
    }
}

// C-frag element (fi,fj,rr): row = m0+w*32+fi*16+kg*4+rr, col = n0+fj*16+lr  [m89-verified]

// ------------------------------------------------------------------ K1: QKV
__global__ __launch_bounds__(256) void k_qkv(
    const u16t* __restrict__ xb, const u16t* __restrict__ WT,
    u16t* __restrict__ qb, u16t* __restrict__ kb, u16t* __restrict__ vT)
{
    __shared__ u16t Als[128 * KP];
    __shared__ u16t Bls[64 * KP];
    int z = blockIdx.z;
    int m0 = blockIdx.y * 128, n0 = blockIdx.x * 64;
    const u16t* A = xb + (size_t)m0 * D_SZ;
    const u16t* Bt = WT + (size_t)z * D_SZ * D_SZ + (size_t)n0 * D_SZ;
    f32x4 acc[2][4] = {};
    gemm_mainloop<4>(A, D_SZ, Bt, D_SZ, D_SZ, threadIdx.x, Als, Bls, acc);
    int w = threadIdx.x >> 6, lane = threadIdx.x & 63, lr = lane & 15, kg = lane >> 4;
#pragma unroll
    for (int fi = 0; fi < 2; ++fi)
#pragma unroll
        for (int fj = 0; fj < 4; ++fj)
#pragma unroll
            for (int rr = 0; rr < 4; ++rr) {
                int row = m0 + w * 32 + fi * 16 + kg * 4 + rr;
                int col = n0 + fj * 16 + lr;
                u16t v = f2b(acc[fi][fj][rr]);
                if (z == 0) {
                    qb[(size_t)row * D_SZ + col] = v;
                } else if (z == 1) {
                    kb[(size_t)row * D_SZ + col] = v;
                } else {
                    int b = row >> 10, s = row & 1023;
                    vT[(((size_t)b * D_SZ + col) << 10) + s] = v;
                }
            }
}

// ------------------------------------- K2a: effective mask matrices (f32)
// Beff[k][0:128]   = sum_d 0.5*(Wq[k][d]+Wq[k][d+256]) * W1[d][:]      (d<256)
// Beff[k][128:256] = sum_d 0.5*(Wk[k][d]+Wk[k][d+256]) * W1[256+d][:]
__global__ void k_eff(const float* __restrict__ Wq, const float* __restrict__ Wk,
                      const float* __restrict__ W1, float* __restrict__ Beff)
{
    int k = blockIdx.x;      // 512
    int t = threadIdx.x;     // 128
    int half = blockIdx.y;
    const float* W = half ? Wk : Wq;
    const float* W1h = W1 + (half ? (size_t)DH * HH : 0);
    __shared__ float wm[256];
    const float* wr = W + (size_t)k * D_SZ;
    for (int d = t; d < 256; d += 128) wm[d] = 0.5f * (wr[d] + wr[d + DH]);
    __syncthreads();
    float s = 0.f;
    for (int d = 0; d < 256; ++d) s += wm[d] * W1h[(size_t)d * HH + t];
    Beff[(size_t)k * 256 + half * 128 + t] = s;
}

// --------------------- K2b: [a|c] = x @ Beff (f32 tiled GEMM), a gets +b1
// tile 64 rows x 32 cols, 256 thr, 4x2 per thread. grid (32, 8).
__global__ __launch_bounds__(256) void k_ac(
    const float* __restrict__ x, const float* __restrict__ Beff,
    const float* __restrict__ b1, float* __restrict__ a, float* __restrict__ cc)
{
    __shared__ float xs[64][68];
    __shared__ float bsT[32][68];   // bsT[n][k]
    int r0 = blockIdx.x * 64, n0 = blockIdx.y * 32;
    int t = threadIdx.x;
    int ti = t >> 4, tj = t & 15;
    float acc[4][2] = {};
    for (int k0 = 0; k0 < 512; k0 += 64) {
        if (k0) __syncthreads();
#pragma unroll
        for (int p = 0; p < 4; ++p) {
            int idx = t + p * 256;
            int r = idx >> 4, c4 = (idx & 15) * 4;
            *(float4*)&xs[r][c4] = *(const float4*)(x + (size_t)(r0 + r) * D_SZ + k0 + c4);
        }
#pragma unroll
        for (int p = 0; p < 2; ++p) {
            int idx = t + p * 256;
            int k = idx >> 3, n4 = (idx & 7) * 4;
            float4 v = *(const float4*)(Beff + (size_t)(k0 + k) * 256 + n0 + n4);
            bsT[n4][k] = v.x; bsT[n4 + 1][k] = v.y; bsT[n4 + 2][k] = v.z; bsT[n4 + 3][k] = v.w;
        }
        __syncthreads();
#pragma unroll
        for (int kk = 0; kk < 16; ++kk) {
            float4 xv[4], bv[2];
#pragma unroll
            for (int ri = 0; ri < 4; ++ri) xv[ri] = *(const float4*)&xs[ti + 16 * ri][kk * 4];
#pragma unroll
            for (int rj = 0; rj < 2; ++rj) bv[rj] = *(const float4*)&bsT[tj + 16 * rj][kk * 4];
#pragma unroll
            for (int ri = 0; ri < 4; ++ri)
#pragma unroll
                for (int rj = 0; rj < 2; ++rj)
                    acc[ri][rj] += xv[ri].x * bv[rj].x + xv[ri].y * bv[rj].y
                                 + xv[ri].z * bv[rj].z + xv[ri].w * bv[rj].w;
        }
    }
    bool isA = n0 < 128;
#pragma unroll
    for (int rj = 0; rj < 2; ++rj) {
        int col = n0 + tj + 16 * rj;
        float badd = isA ? b1[col] : 0.f;
#pragma unroll
        for (int ri = 0; ri < 4; ++ri) {
            int row = r0 + ti + 16 * ri;
            if (isA) a[(size_t)row * HH + col] = acc[ri][rj] + badd;
            else     cc[(size_t)row * HH + (col - 128)] = acc[ri][rj];
        }
    }
}

// ------------------------------------------------------------- K3: mask bits
// 64x64 (i,j) tile per block, 4x4 per thread (strided i=ti+16ri, j=tj+16rj).
// a already has b1 folded in; b2 folded into acc init.
__global__ __launch_bounds__(256) void k_mask(
    const float* __restrict__ a, const float* __restrict__ c,
    const float* __restrict__ W2, const float* __restrict__ b2,
    unsigned char* __restrict__ maskb)
{
    __shared__ __align__(16) float at[64][132];
    __shared__ __align__(16) float ct[64][132];
    __shared__ __align__(16) float w2s[128];
    int b = blockIdx.z, i0 = blockIdx.y * 64, j0 = blockIdx.x * 64;
    int t = threadIdx.x;
    if (t < 128) w2s[t] = W2[t];
#pragma unroll
    for (int p = 0; p < 8; ++p) {
        int idx = t + p * 256;               // 0..2047
        int r = idx >> 5, c4 = (idx & 31) * 4;
        *(float4*)&at[r][c4] = *(const float4*)(a + ((size_t)(b * S_SZ + i0 + r)) * HH + c4);
        *(float4*)&ct[r][c4] = *(const float4*)(c + ((size_t)(b * S_SZ + j0 + r)) * HH + c4);
    }
    __syncthreads();
    float fb2 = b2[0];
    int ti = t >> 4, tj = t & 15;
    float acc[4][4];
#pragma unroll
    for (int ri = 0; ri < 4; ++ri)
#pragma unroll
        for (int rj = 0; rj < 4; ++rj) acc[ri][rj] = fb2;
#pragma unroll 2
    for (int h4 = 0; h4 < 32; ++h4) {
        float4 av[4], cv[4];
        float4 wv = ((const float4*)w2s)[h4];
#pragma unroll
        for (int ri = 0; ri < 4; ++ri) av[ri] = *(const float4*)&at[ti + 16 * ri][h4 * 4];
#pragma unroll
        for (int rj = 0; rj < 4; ++rj) cv[rj] = *(const float4*)&ct[tj + 16 * rj][h4 * 4];
#pragma unroll
        for (int ri = 0; ri < 4; ++ri)
#pragma unroll
            for (int rj = 0; rj < 4; ++rj) {
                acc[ri][rj] += fmaxf(av[ri].x + cv[rj].x, 0.f) * wv.x;
                acc[ri][rj] += fmaxf(av[ri].y + cv[rj].y, 0.f) * wv.y;
                acc[ri][rj] += fmaxf(av[ri].z + cv[rj].z, 0.f) * wv.z;
                acc[ri][rj] += fmaxf(av[ri].w + cv[rj].w, 0.f) * wv.w;
            }
    }
#pragma unroll
    for (int ri = 0; ri < 4; ++ri)
#pragma unroll
        for (int rj = 0; rj < 4; ++rj) {
            int i = i0 + ti + 16 * ri, j = j0 + tj + 16 * rj;
            maskb[((size_t)b << 20) + ((size_t)i << 10) + j] = acc[ri][rj] > 0.f ? 1 : 0;
        }
}

// ---------------------------------------------------- K4: scores (masked QK^T)
__global__ __launch_bounds__(256) void k_scores(
    const u16t* __restrict__ qb, const u16t* __restrict__ kb,
    const unsigned char* __restrict__ maskb, float* __restrict__ scores)
{
    __shared__ u16t Als[128 * KP];
    __shared__ u16t Bls[64 * KP];
    int bh = blockIdx.z, b = bh >> 1, h = bh & 1;
    int m0 = blockIdx.y * 128, n0 = blockIdx.x * 64;
    const u16t* A = qb + (size_t)b * S_SZ * D_SZ + (size_t)m0 * D_SZ + h * DH;
    const u16t* Bt = kb + (size_t)b * S_SZ * D_SZ + (size_t)n0 * D_SZ + h * DH;
    f32x4 acc[2][4] = {};
    gemm_mainloop<4>(A, D_SZ, Bt, D_SZ, DH, threadIdx.x, Als, Bls, acc);
    int w = threadIdx.x >> 6, lane = threadIdx.x & 63, lr = lane & 15, kg = lane >> 4;
#pragma unroll
    for (int fi = 0; fi < 2; ++fi)
#pragma unroll
        for (int fj = 0; fj < 4; ++fj)
#pragma unroll
            for (int rr = 0; rr < 4; ++rr) {
                int i = m0 + w * 32 + fi * 16 + kg * 4 + rr;
                int j = n0 + fj * 16 + lr;
                float v = acc[fi][fj][rr] * 0.0625f;  // 1/sqrt(256)
                bool msk = maskb[((size_t)b << 20) + ((size_t)i << 10) + j] != 0;
                scores[((size_t)bh << 20) + ((size_t)i << 10) + j] = msk ? v : -1e9f;
            }
}

// --------------------------------------------------------------- K5: softmax
__global__ void k_softmax(const float* __restrict__ scores, u16t* __restrict__ P) {
    int row = blockIdx.x;  // (b*2+h)*1024 + i
    int t = threadIdx.x;
    const float* src = scores + ((size_t)row << 10);
    float4 v = ((const float4*)src)[t];
    float m = fmaxf(fmaxf(v.x, v.y), fmaxf(v.z, v.w));
    for (int o = 32; o; o >>= 1) m = fmaxf(m, __shfl_xor(m, o));
    __shared__ float redm[4];
    __shared__ float reds[4];
    int w = t >> 6;
    if ((t & 63) == 0) redm[w] = m;
    __syncthreads();
    m = fmaxf(fmaxf(redm[0], redm[1]), fmaxf(redm[2], redm[3]));
    float e0 = expf(v.x - m), e1 = expf(v.y - m), e2 = expf(v.z - m), e3 = expf(v.w - m);
    float s = e0 + e1 + e2 + e3;
    for (int o = 32; o; o >>= 1) s += __shfl_xor(s, o);
    if ((t & 63) == 0) reds[w] = s;
    __syncthreads();
    s = reds[0] + reds[1] + reds[2] + reds[3];
    float inv = 1.0f / s;
    u16t o4[4] = { f2b(e0 * inv), f2b(e1 * inv), f2b(e2 * inv), f2b(e3 * inv) };
    *(ushort4*)(P + ((size_t)row << 10) + t * 4) = *(ushort4*)o4;
}

// -------------------------------------------------------------------- K6: PV
__global__ __launch_bounds__(256) void k_pv(
    const u16t* __restrict__ P, const u16t* __restrict__ vT, u16t* __restrict__ ao)
{
    __shared__ u16t Als[128 * KP];
    __shared__ u16t Bls[32 * KP];
    int bh = blockIdx.z, b = bh >> 1, h = bh & 1;
    int m0 = blockIdx.y * 128, n0 = blockIdx.x * 32;
    const u16t* A = P + ((size_t)bh << 20) + (size_t)m0 * S_SZ;
    const u16t* Bt = vT + ((size_t)(b * D_SZ + h * DH + n0)) * S_SZ;
    f32x4 acc[2][2] = {};
    gemm_mainloop<2>(A, S_SZ, Bt, S_SZ, S_SZ, threadIdx.x, Als, Bls, acc);
    int w = threadIdx.x >> 6, lane = threadIdx.x & 63, lr = lane & 15, kg = lane >> 4;
#pragma unroll
    for (int fi = 0; fi < 2; ++fi)
#pragma unroll
        for (int fj = 0; fj < 2; ++fj)
#pragma unroll
            for (int rr = 0; rr < 4; ++rr) {
                int i = m0 + w * 32 + fi * 16 + kg * 4 + rr;
                int d = n0 + fj * 16 + lr;  // within head
                ao[((size_t)(b * S_SZ + i)) * D_SZ + h * DH + d] = f2b(acc[fi][fj][rr]);
            }
}

// ------------------------------------------------------------ K7: out = ao@Wo+bo
__global__ __launch_bounds__(256) void k_out(
    const u16t* __restrict__ ao, const u16t* __restrict__ WoT,
    const float* __restrict__ bo, float* __restrict__ out)
{
    __shared__ u16t Als[128 * KP];
    __shared__ u16t Bls[32 * KP];
    int m0 = blockIdx.y * 128, n0 = blockIdx.x * 32;
    const u16t* A = ao + (size_t)m0 * D_SZ;
    const u16t* Bt = WoT + (size_t)n0 * D_SZ;
    f32x4 acc[2][2] = {};
    gemm_mainloop<2>(A, D_SZ, Bt, D_SZ, D_SZ, threadIdx.x, Als, Bls, acc);
    int w = threadIdx.x >> 6, lane = threadIdx.x & 63, lr = lane & 15, kg = lane >> 4;
#pragma unroll
    for (int fi = 0; fi < 2; ++fi)
#pragma unroll
        for (int fj = 0; fj < 2; ++fj)
#pragma unroll
            for (int rr = 0; rr < 4; ++rr) {
                int row = m0 + w * 32 + fi * 16 + kg * 4 + rr;
                int col = n0 + fj * 16 + lr;
                out[(size_t)row * D_SZ + col] = acc[fi][fj][rr] + bo[col];
            }
}

// ---------------------------------------------------------------------- host
extern "C" void kernel_launch(void* const* d_in, const int* in_sizes, int n_in,
                              void* d_out, int out_size, void* d_ws, size_t ws_size,
                              hipStream_t stream)
{
    const float* x  = (const float*)d_in[0];
    const float* Wmat[4] = { (const float*)d_in[1], (const float*)d_in[2],
                             (const float*)d_in[3], (const float*)d_in[4] };
    const float* bo = (const float*)d_in[5];
    const float* W1 = (const float*)d_in[6];
    const float* b1 = (const float*)d_in[7];
    const float* W2 = (const float*)d_in[8];
    const float* b2 = (const float*)d_in[9];
    float* out = (float*)d_out;

    // workspace carve (all 256B-aligned)
    char* ws = (char*)d_ws;
    size_t off = 0;
    auto carve = [&](size_t bytes) { void* p = ws + off; off += (bytes + 255) & ~(size_t)255; return p; };
    u16t* xb   = (u16t*)carve((size_t)2048 * 512 * 2);
    u16t* WT   = (u16t*)carve((size_t)4 * 512 * 512 * 2);
    u16t* qb   = (u16t*)carve((size_t)2048 * 512 * 2);
    u16t* kb   = (u16t*)carve((size_t)2048 * 512 * 2);
    u16t* vT   = (u16t*)carve((size_t)2 * 512 * 1024 * 2);
    float* Beff = (float*)carve((size_t)512 * 256 * 4);
    float* a   = (float*)carve((size_t)2048 * 128 * 4);
    float* c   = (float*)carve((size_t)2048 * 128 * 4);
    unsigned char* maskb = (unsigned char*)carve((size_t)2 * 1024 * 1024);
    float* scores = (float*)carve((size_t)4 * 1024 * 1024 * 4);
    u16t* P    = (u16t*)carve((size_t)4 * 1024 * 1024 * 2);
    u16t* ao   = (u16t*)carve((size_t)2048 * 512 * 2);
    (void)ws_size;

    k_xconv<<<dim3(1024), dim3(256), 0, stream>>>(x, xb);
    for (int z = 0; z < 4; ++z)
        k_trans<<<dim3(16, 16), dim3(256), 0, stream>>>(Wmat[z], WT + (size_t)z * 512 * 512);
    k_qkv<<<dim3(8, 16, 3), dim3(256), 0, stream>>>(xb, WT, qb, kb, vT);
    k_eff<<<dim3(512, 2), dim3(128), 0, stream>>>(Wmat[0], Wmat[1], W1, Beff);
    k_ac<<<dim3(32, 8), dim3(256), 0, stream>>>(x, Beff, b1, a, c);
    k_mask<<<dim3(16, 16, 2), dim3(256), 0, stream>>>(a, c, W2, b2, maskb);
    k_scores<<<dim3(16, 8, 4), dim3(256), 0, stream>>>(qb, kb, maskb, scores);
    k_softmax<<<dim3(4096), dim3(256), 0, stream>>>(scores, P);
    k_pv<<<dim3(8, 8, 4), dim3(256), 0, stream>>>(P, vT, ao);
    k_out<<<dim3(16, 16), dim3(256), 0, stream>>>(ao, WT + (size_t)3 * 512 * 512, bo, out);
}

// Round 4
// 120.770 us; speedup vs baseline: 2.7237x; 1.1127x over previous
//
#include <hip/hip_runtime.h>

// AdaptiveSparsityAttention on MI355X (gfx950).
// f32 in/out, internal bf16 MFMA for attention; mask logits in pure f32 via
// algebraic fusion:  a = x @ (0.5*(Wq[:,:256]+Wq[:,256:]) @ W1[:256]) + b1.
//
// R4: - k_prep fuses xconv + 4x trans + eff (13 -> 8 launches)
//     - k_qkv z==2: LDS-transposed coalesced vT writes (was 2B scatter @ 2KB stride)
//     - scores stored bf16; 1/16 scale folded into qb

typedef unsigned short u16t;
typedef __bf16 bf16x8 __attribute__((ext_vector_type(8)));
typedef float f32x4 __attribute__((ext_vector_type(4)));

#define B_SZ 2
#define S_SZ 1024
#define D_SZ 512
#define DH 256
#define HH 128   // hidden dim of sparsity predictor

static __device__ __forceinline__ u16t f2b(float f) {
    unsigned int u = __builtin_bit_cast(unsigned int, f);
    u += 0x7FFFu + ((u >> 16) & 1u);
    return (u16t)(u >> 16);
}
static __device__ __forceinline__ float b2f(u16t u) {
    return __builtin_bit_cast(float, (unsigned int)u << 16);
}

static __device__ __forceinline__ f32x4 mfma16(bf16x8 a, bf16x8 b, f32x4 c) {
    return __builtin_amdgcn_mfma_f32_16x16x32_bf16(a, b, c, 0, 0, 0);
}

// ---------------------------------------------------------- K0: fused prep
// blocks [0,1024): x->bf16 | [1024,2048): W transposes | [2048,2560): Beff
__global__ __launch_bounds__(256) void k_prep(
    const float* __restrict__ x,
    const float* __restrict__ Wq, const float* __restrict__ Wk,
    const float* __restrict__ Wv, const float* __restrict__ Wo,
    const float* __restrict__ W1,
    u16t* __restrict__ xb, u16t* __restrict__ WT, float* __restrict__ Beff)
{
    __shared__ float smf[1088];   // union: tile[32][33] (trans) | wm[2][256] (eff)
    int bidx = blockIdx.x;
    int t = threadIdx.x;
    if (bidx < 1024) {
        int idx = (bidx * 256 + t) * 4;
        float4 v = *(const float4*)(x + idx);
        u16t* o = xb + idx;
        o[0] = f2b(v.x); o[1] = f2b(v.y); o[2] = f2b(v.z); o[3] = f2b(v.w);
    } else if (bidx < 2048) {
        int t2 = bidx - 1024;
        int z = t2 >> 8, rem = t2 & 255;
        int n0 = (rem & 15) * 32, k0 = (rem >> 4) * 32;
        const float* W = z == 0 ? Wq : z == 1 ? Wk : z == 2 ? Wv : Wo;
        u16t* WTz = WT + (size_t)z * D_SZ * D_SZ;
        float (*tile)[33] = (float(*)[33])smf;
        int r = t >> 3, c4 = (t & 7) * 4;
        float4 v = *(const float4*)(W + (size_t)(k0 + r) * D_SZ + n0 + c4);
        tile[r][c4] = v.x; tile[r][c4 + 1] = v.y; tile[r][c4 + 2] = v.z; tile[r][c4 + 3] = v.w;
        __syncthreads();
        u16t o[4];
        o[0] = f2b(tile[c4][r]); o[1] = f2b(tile[c4 + 1][r]);
        o[2] = f2b(tile[c4 + 2][r]); o[3] = f2b(tile[c4 + 3][r]);
        *(ushort4*)(WTz + (size_t)(n0 + r) * D_SZ + k0 + c4) = *(ushort4*)o;
    } else {
        int k = bidx - 2048;   // 0..511
        float* wm0 = smf;
        float* wm1 = smf + 256;
        const float* wrq = Wq + (size_t)k * D_SZ;
        const float* wrk = Wk + (size_t)k * D_SZ;
        wm0[t & 255] = 0.5f * (wrq[t & 255] + wrq[(t & 255) + DH]);
        wm1[t & 255] = 0.5f * (wrk[t & 255] + wrk[(t & 255) + DH]);
        __syncthreads();
        int half = t >> 7, hcol = t & 127;
        const float* wm = half ? wm1 : wm0;
        const float* W1h = W1 + (half ? (size_t)DH * HH : 0);
        float s = 0.f;
        for (int d = 0; d < 256; ++d) s += wm[d] * W1h[(size_t)d * HH + hcol];
        Beff[(size_t)k * 256 + half * 128 + hcol] = s;
    }
}

// ------------------------------------------------------------- GEMM mainloop
// C[BM=128][BN=NF*16] per block (256 thr, 4 waves; wave w owns rows w*32..+32).
// A: [M][K] k-contig (pre-offset to row m0), B: [N][K] k-contig (pre-offset to n0).
#define KP 72  // padded LDS row stride (bf16 elems)

template<int NF>
static __device__ __forceinline__ void gemm_mainloop(
    const u16t* __restrict__ A, int lda, const u16t* __restrict__ B, int ldb,
    int K, int tid, u16t* Als, u16t* Bls, f32x4 acc[2][NF])
{
    const int w = tid >> 6, lane = tid & 63;
    const int lr = lane & 15, kg = lane >> 4;
    for (int k0 = 0; k0 < K; k0 += 64) {
        if (k0) __syncthreads();
        {
            int c = tid & 7, r0 = tid >> 3;
#pragma unroll
            for (int p = 0; p < 4; ++p) {
                int r = r0 + p * 32;
                *(uint4*)(&Als[r * KP + c * 8]) = *(const uint4*)(&A[(size_t)r * lda + k0 + c * 8]);
            }
#pragma unroll
            for (int p = 0; p < NF / 2; ++p) {
                int r = r0 + p * 32;
                *(uint4*)(&Bls[r * KP + c * 8]) = *(const uint4*)(&B[(size_t)r * ldb + k0 + c * 8]);
            }
        }
        __syncthreads();
#pragma unroll
        for (int kk = 0; kk < 2; ++kk) {
            bf16x8 af[2], bfr[NF];
#pragma unroll
            for (int fi = 0; fi < 2; ++fi)
                af[fi] = *(const bf16x8*)(&Als[(w * 32 + fi * 16 + lr) * KP + kk * 32 + kg * 8]);
#pragma unroll
            for (int fj = 0; fj < NF; ++fj)
                bfr[fj] = *(const bf16x8*)(&Bls[(fj * 16 + lr) * KP + kk * 32 + kg * 8]);
#pragma unroll
            for (int fi = 0; fi < 2; ++fi)
#pragma unroll
                for (int fj = 0; fj < NF; ++fj)
                    acc[fi][fj] = mfma16(af[fi], bfr[fj], acc[fi][fj]);
        }
    }
}

// C-frag element (fi,fj,rr): row = m0+w*32+fi*16+kg*4+rr, col = n0+fj*16+lr  [m89-verified]

// ------------------------------------------------------------------ K1: QKV
// z==0 writes qb pre-scaled by 1/16 (absorbs the 1/sqrt(dh) of scores).
__global__ __launch_bounds__(256) void k_qkv(
    const u16t* __restrict__ xb, const u16t* __restrict__ WT,
    u16t* __restrict__ qb, u16t* __restrict__ kb, u16t* __restrict__ vT)
{
    __shared__ u16t Als[128 * KP];
    __shared__ u16t Bls[64 * KP];
    int z = blockIdx.z;
    int m0 = blockIdx.y * 128, n0 = blockIdx.x * 64;
    const u16t* A = xb + (size_t)m0 * D_SZ;
    const u16t* Bt = WT + (size_t)z * D_SZ * D_SZ + (size_t)n0 * D_SZ;
    f32x4 acc[2][4] = {};
    gemm_mainloop<4>(A, D_SZ, Bt, D_SZ, D_SZ, threadIdx.x, Als, Bls, acc);
    int w = threadIdx.x >> 6, lane = threadIdx.x & 63, lr = lane & 15, kg = lane >> 4;
    if (z < 2) {
        u16t* dst = z == 0 ? qb : kb;
        float scale = z == 0 ? 0.0625f : 1.0f;
#pragma unroll
        for (int fi = 0; fi < 2; ++fi)
#pragma unroll
            for (int fj = 0; fj < 4; ++fj)
#pragma unroll
                for (int rr = 0; rr < 4; ++rr) {
                    int row = m0 + w * 32 + fi * 16 + kg * 4 + rr;
                    int col = n0 + fj * 16 + lr;
                    dst[(size_t)row * D_SZ + col] = f2b(acc[fi][fj][rr] * scale);
                }
    } else {
        // stage to LDS, write vT with s-contiguous coalesced runs
        __syncthreads();
        u16t (*vls)[136] = (u16t(*)[136])Als;   // 64*136 = 8704 <= 128*72
#pragma unroll
        for (int fi = 0; fi < 2; ++fi)
#pragma unroll
            for (int fj = 0; fj < 4; ++fj)
#pragma unroll
                for (int rr = 0; rr < 4; ++rr)
                    vls[fj * 16 + lr][w * 32 + fi * 16 + kg * 4 + rr] = f2b(acc[fi][fj][rr]);
        __syncthreads();
        int b = m0 >> 10, s0 = m0 & 1023;
        int cr = threadIdx.x >> 2, seg = threadIdx.x & 3;
        const u16t* srcp = &vls[cr][seg * 32];
        u16t* dstp = vT + (((size_t)(b * D_SZ + n0 + cr)) << 10) + s0 + seg * 32;
#pragma unroll
        for (int qq = 0; qq < 4; ++qq)
            *(uint4*)(dstp + qq * 8) = *(const uint4*)(srcp + qq * 8);
    }
}

// --------------------- K2: [a|c] = x @ Beff (f32 tiled GEMM), a gets +b1
// tile 64 rows x 32 cols, 256 thr, 4x2 per thread. grid (32, 8).
__global__ __launch_bounds__(256) void k_ac(
    const float* __restrict__ x, const float* __restrict__ Beff,
    const float* __restrict__ b1, float* __restrict__ a, float* __restrict__ cc)
{
    __shared__ float xs[64][68];
    __shared__ float bsT[32][68];   // bsT[n][k]
    int r0 = blockIdx.x * 64, n0 = blockIdx.y * 32;
    int t = threadIdx.x;
    int ti = t >> 4, tj = t & 15;
    float acc[4][2] = {};
    for (int k0 = 0; k0 < 512; k0 += 64) {
        if (k0) __syncthreads();
#pragma unroll
        for (int p = 0; p < 4; ++p) {
            int idx = t + p * 256;
            int r = idx >> 4, c4 = (idx & 15) * 4;
            *(float4*)&xs[r][c4] = *(const float4*)(x + (size_t)(r0 + r) * D_SZ + k0 + c4);
        }
#pragma unroll
        for (int p = 0; p < 2; ++p) {
            int idx = t + p * 256;
            int k = idx >> 3, n4 = (idx & 7) * 4;
            float4 v = *(const float4*)(Beff + (size_t)(k0 + k) * 256 + n0 + n4);
            bsT[n4][k] = v.x; bsT[n4 + 1][k] = v.y; bsT[n4 + 2][k] = v.z; bsT[n4 + 3][k] = v.w;
        }
        __syncthreads();
#pragma unroll
        for (int kk = 0; kk < 16; ++kk) {
            float4 xv[4], bv[2];
#pragma unroll
            for (int ri = 0; ri < 4; ++ri) xv[ri] = *(const float4*)&xs[ti + 16 * ri][kk * 4];
#pragma unroll
            for (int rj = 0; rj < 2; ++rj) bv[rj] = *(const float4*)&bsT[tj + 16 * rj][kk * 4];
#pragma unroll
            for (int ri = 0; ri < 4; ++ri)
#pragma unroll
                for (int rj = 0; rj < 2; ++rj)
                    acc[ri][rj] += xv[ri].x * bv[rj].x + xv[ri].y * bv[rj].y
                                 + xv[ri].z * bv[rj].z + xv[ri].w * bv[rj].w;
        }
    }
    bool isA = n0 < 128;
#pragma unroll
    for (int rj = 0; rj < 2; ++rj) {
        int col = n0 + tj + 16 * rj;
        float badd = isA ? b1[col] : 0.f;
#pragma unroll
        for (int ri = 0; ri < 4; ++ri) {
            int row = r0 + ti + 16 * ri;
            if (isA) a[(size_t)row * HH + col] = acc[ri][rj] + badd;
            else     cc[(size_t)row * HH + (col - 128)] = acc[ri][rj];
        }
    }
}

// ------------------------------------------------------------- K3: mask bits
// 64x64 (i,j) tile per block, 4x4 per thread (strided i=ti+16ri, j=tj+16rj).
// a already has b1 folded in; b2 folded into acc init.
__global__ __launch_bounds__(256) void k_mask(
    const float* __restrict__ a, const float* __restrict__ c,
    const float* __restrict__ W2, const float* __restrict__ b2,
    unsigned char* __restrict__ maskb)
{
    __shared__ __align__(16) float at[64][132];
    __shared__ __align__(16) float ct[64][132];
    __shared__ __align__(16) float w2s[128];
    int b = blockIdx.z, i0 = blockIdx.y * 64, j0 = blockIdx.x * 64;
    int t = threadIdx.x;
    if (t < 128) w2s[t] = W2[t];
#pragma unroll
    for (int p = 0; p < 8; ++p) {
        int idx = t + p * 256;               // 0..2047
        int r = idx >> 5, c4 = (idx & 31) * 4;
        *(float4*)&at[r][c4] = *(const float4*)(a + ((size_t)(b * S_SZ + i0 + r)) * HH + c4);
        *(float4*)&ct[r][c4] = *(const float4*)(c + ((size_t)(b * S_SZ + j0 + r)) * HH + c4);
    }
    __syncthreads();
    float fb2 = b2[0];
    int ti = t >> 4, tj = t & 15;
    float acc[4][4];
#pragma unroll
    for (int ri = 0; ri < 4; ++ri)
#pragma unroll
        for (int rj = 0; rj < 4; ++rj) acc[ri][rj] = fb2;
#pragma unroll 2
    for (int h4 = 0; h4 < 32; ++h4) {
        float4 av[4], cv[4];
        float4 wv = ((const float4*)w2s)[h4];
#pragma unroll
        for (int ri = 0; ri < 4; ++ri) av[ri] = *(const float4*)&at[ti + 16 * ri][h4 * 4];
#pragma unroll
        for (int rj = 0; rj < 4; ++rj) cv[rj] = *(const float4*)&ct[tj + 16 * rj][h4 * 4];
#pragma unroll
        for (int ri = 0; ri < 4; ++ri)
#pragma unroll
            for (int rj = 0; rj < 4; ++rj) {
                acc[ri][rj] += fmaxf(av[ri].x + cv[rj].x, 0.f) * wv.x;
                acc[ri][rj] += fmaxf(av[ri].y + cv[rj].y, 0.f) * wv.y;
                acc[ri][rj] += fmaxf(av[ri].z + cv[rj].z, 0.f) * wv.z;
                acc[ri][rj] += fmaxf(av[ri].w + cv[rj].w, 0.f) * wv.w;
            }
    }
#pragma unroll
    for (int ri = 0; ri < 4; ++ri)
#pragma unroll
        for (int rj = 0; rj < 4; ++rj) {
            int i = i0 + ti + 16 * ri, j = j0 + tj + 16 * rj;
            maskb[((size_t)b << 20) + ((size_t)i << 10) + j] = acc[ri][rj] > 0.f ? 1 : 0;
        }
}

// ---------------------------------------------------- K4: scores (masked QK^T)
// qb is pre-scaled by 1/16; output bf16 (masked -> bf16(-1e9)).
__global__ __launch_bounds__(256) void k_scores(
    const u16t* __restrict__ qb, const u16t* __restrict__ kb,
    const unsigned char* __restrict__ maskb, u16t* __restrict__ scores)
{
    __shared__ u16t Als[128 * KP];
    __shared__ u16t Bls[64 * KP];
    int bh = blockIdx.z, b = bh >> 1, h = bh & 1;
    int m0 = blockIdx.y * 128, n0 = blockIdx.x * 64;
    const u16t* A = qb + (size_t)b * S_SZ * D_SZ + (size_t)m0 * D_SZ + h * DH;
    const u16t* Bt = kb + (size_t)b * S_SZ * D_SZ + (size_t)n0 * D_SZ + h * DH;
    f32x4 acc[2][4] = {};
    gemm_mainloop<4>(A, D_SZ, Bt, D_SZ, DH, threadIdx.x, Als, Bls, acc);
    int w = threadIdx.x >> 6, lane = threadIdx.x & 63, lr = lane & 15, kg = lane >> 4;
    const u16t NEG = f2b(-1e9f);
#pragma unroll
    for (int fi = 0; fi < 2; ++fi)
#pragma unroll
        for (int fj = 0; fj < 4; ++fj)
#pragma unroll
            for (int rr = 0; rr < 4; ++rr) {
                int i = m0 + w * 32 + fi * 16 + kg * 4 + rr;
                int j = n0 + fj * 16 + lr;
                bool msk = maskb[((size_t)b << 20) + ((size_t)i << 10) + j] != 0;
                scores[((size_t)bh << 20) + ((size_t)i << 10) + j]
                    = msk ? f2b(acc[fi][fj][rr]) : NEG;
            }
}

// --------------------------------------------------------------- K5: softmax
__global__ void k_softmax(const u16t* __restrict__ scores, u16t* __restrict__ P) {
    int row = blockIdx.x;  // (b*2+h)*1024 + i
    int t = threadIdx.x;
    const u16t* src = scores + ((size_t)row << 10);
    ushort4 raw = ((const ushort4*)src)[t];
    float v0 = b2f(raw.x), v1 = b2f(raw.y), v2 = b2f(raw.z), v3 = b2f(raw.w);
    float m = fmaxf(fmaxf(v0, v1), fmaxf(v2, v3));
    for (int o = 32; o; o >>= 1) m = fmaxf(m, __shfl_xor(m, o));
    __shared__ float redm[4];
    __shared__ float reds[4];
    int w = t >> 6;
    if ((t & 63) == 0) redm[w] = m;
    __syncthreads();
    m = fmaxf(fmaxf(redm[0], redm[1]), fmaxf(redm[2], redm[3]));
    float e0 = expf(v0 - m), e1 = expf(v1 - m), e2 = expf(v2 - m), e3 = expf(v3 - m);
    float s = e0 + e1 + e2 + e3;
    for (int o = 32; o; o >>= 1) s += __shfl_xor(s, o);
    if ((t & 63) == 0) reds[w] = s;
    __syncthreads();
    s = reds[0] + reds[1] + reds[2] + reds[3];
    float inv = 1.0f / s;
    u16t o4[4] = { f2b(e0 * inv), f2b(e1 * inv), f2b(e2 * inv), f2b(e3 * inv) };
    *(ushort4*)(P + ((size_t)row << 10) + t * 4) = *(ushort4*)o4;
}

// -------------------------------------------------------------------- K6: PV
__global__ __launch_bounds__(256) void k_pv(
    const u16t* __restrict__ P, const u16t* __restrict__ vT, u16t* __restrict__ ao)
{
    __shared__ u16t Als[128 * KP];
    __shared__ u16t Bls[32 * KP];
    int bh = blockIdx.z, b = bh >> 1, h = bh & 1;
    int m0 = blockIdx.y * 128, n0 = blockIdx.x * 32;
    const u16t* A = P + ((size_t)bh << 20) + (size_t)m0 * S_SZ;
    const u16t* Bt = vT + ((size_t)(b * D_SZ + h * DH + n0)) * S_SZ;
    f32x4 acc[2][2] = {};
    gemm_mainloop<2>(A, S_SZ, Bt, S_SZ, S_SZ, threadIdx.x, Als, Bls, acc);
    int w = threadIdx.x >> 6, lane = threadIdx.x & 63, lr = lane & 15, kg = lane >> 4;
#pragma unroll
    for (int fi = 0; fi < 2; ++fi)
#pragma unroll
        for (int fj = 0; fj < 2; ++fj)
#pragma unroll
            for (int rr = 0; rr < 4; ++rr) {
                int i = m0 + w * 32 + fi * 16 + kg * 4 + rr;
                int d = n0 + fj * 16 + lr;  // within head
                ao[((size_t)(b * S_SZ + i)) * D_SZ + h * DH + d] = f2b(acc[fi][fj][rr]);
            }
}

// ------------------------------------------------------------ K7: out = ao@Wo+bo
__global__ __launch_bounds__(256) void k_out(
    const u16t* __restrict__ ao, const u16t* __restrict__ WoT,
    const float* __restrict__ bo, float* __restrict__ out)
{
    __shared__ u16t Als[128 * KP];
    __shared__ u16t Bls[32 * KP];
    int m0 = blockIdx.y * 128, n0 = blockIdx.x * 32;
    const u16t* A = ao + (size_t)m0 * D_SZ;
    const u16t* Bt = WoT + (size_t)n0 * D_SZ;
    f32x4 acc[2][2] = {};
    gemm_mainloop<2>(A, D_SZ, Bt, D_SZ, D_SZ, threadIdx.x, Als, Bls, acc);
    int w = threadIdx.x >> 6, lane = threadIdx.x & 63, lr = lane & 15, kg = lane >> 4;
#pragma unroll
    for (int fi = 0; fi < 2; ++fi)
#pragma unroll
        for (int fj = 0; fj < 2; ++fj)
#pragma unroll
            for (int rr = 0; rr < 4; ++rr) {
                int row = m0 + w * 32 + fi * 16 + kg * 4 + rr;
                int col = n0 + fj * 16 + lr;
                out[(size_t)row * D_SZ + col] = acc[fi][fj][rr] + bo[col];
            }
}

// ---------------------------------------------------------------------- host
extern "C" void kernel_launch(void* const* d_in, const int* in_sizes, int n_in,
                              void* d_out, int out_size, void* d_ws, size_t ws_size,
                              hipStream_t stream)
{
    const float* x  = (const float*)d_in[0];
    const float* Wq = (const float*)d_in[1];
    const float* Wk = (const float*)d_in[2];
    const float* Wv = (const float*)d_in[3];
    const float* Wo = (const float*)d_in[4];
    const float* bo = (const float*)d_in[5];
    const float* W1 = (const float*)d_in[6];
    const float* b1 = (const float*)d_in[7];
    const float* W2 = (const float*)d_in[8];
    const float* b2 = (const float*)d_in[9];
    float* out = (float*)d_out;

    // workspace carve (all 256B-aligned)
    char* ws = (char*)d_ws;
    size_t off = 0;
    auto carve = [&](size_t bytes) { void* p = ws + off; off += (bytes + 255) & ~(size_t)255; return p; };
    u16t* xb   = (u16t*)carve((size_t)2048 * 512 * 2);
    u16t* WT   = (u16t*)carve((size_t)4 * 512 * 512 * 2);
    u16t* qb   = (u16t*)carve((size_t)2048 * 512 * 2);
    u16t* kb   = (u16t*)carve((size_t)2048 * 512 * 2);
    u16t* vT   = (u16t*)carve((size_t)2 * 512 * 1024 * 2);
    float* Beff = (float*)carve((size_t)512 * 256 * 4);
    float* a   = (float*)carve((size_t)2048 * 128 * 4);
    float* c   = (float*)carve((size_t)2048 * 128 * 4);
    unsigned char* maskb = (unsigned char*)carve((size_t)2 * 1024 * 1024);
    u16t* scores = (u16t*)carve((size_t)4 * 1024 * 1024 * 2);
    u16t* P    = (u16t*)carve((size_t)4 * 1024 * 1024 * 2);
    u16t* ao   = (u16t*)carve((size_t)2048 * 512 * 2);
    (void)ws_size;

    k_prep<<<dim3(2560), dim3(256), 0, stream>>>(x, Wq, Wk, Wv, Wo, W1, xb, WT, Beff);
    k_qkv<<<dim3(8, 16, 3), dim3(256), 0, stream>>>(xb, WT, qb, kb, vT);
    k_ac<<<dim3(32, 8), dim3(256), 0, stream>>>(x, Beff, b1, a, c);
    k_mask<<<dim3(16, 16, 2), dim3(256), 0, stream>>>(a, c, W2, b2, maskb);
    k_scores<<<dim3(16, 8, 4), dim3(256), 0, stream>>>(qb, kb, maskb, scores);
    k_softmax<<<dim3(4096), dim3(256), 0, stream>>>(scores, P);
    k_pv<<<dim3(8, 8, 4), dim3(256), 0, stream>>>(P, vT, ao);
    k_out<<<dim3(16, 16), dim3(256), 0, stream>>>(ao, WT + (size_t)3 * 512 * 512, bo, out);
}

// Round 5
// 112.227 us; speedup vs baseline: 2.9311x; 1.0761x over previous
//
#include <hip/hip_runtime.h>

// AdaptiveSparsityAttention on MI355X (gfx950).
// f32 in/out, internal bf16 MFMA for attention; mask logits in pure f32 via
// algebraic fusion:  a = x @ (0.5*(Wq[:,:256]+Wq[:,256:]) @ W1[:256]) + b1.
//
// R5: - softmax deleted: k_scores writes exp(s) (P_unnorm, bf16) + per-jblock
//       row-sum partials; k_pv applies diag(1/l) in its epilogue (O = P V / l).
//       No max-subtraction needed (|s| ~ O(1)); masked -> exp = 0 exactly.
//     - k_qkv + k_ac fused into one 1D launch (640 blocks).
//     - all epilogues LDS-staged for 128B-coalesced stores (qb/kb/P/ao/out).
// 6 launches: prep, qkvac, mask, scores, pv, out.

typedef unsigned short u16t;
typedef __bf16 bf16x8 __attribute__((ext_vector_type(8)));
typedef float f32x4 __attribute__((ext_vector_type(4)));

#define B_SZ 2
#define S_SZ 1024
#define D_SZ 512
#define DH 256
#define HH 128   // hidden dim of sparsity predictor

static __device__ __forceinline__ u16t f2b(float f) {
    unsigned int u = __builtin_bit_cast(unsigned int, f);
    u += 0x7FFFu + ((u >> 16) & 1u);
    return (u16t)(u >> 16);
}

static __device__ __forceinline__ f32x4 mfma16(bf16x8 a, bf16x8 b, f32x4 c) {
    return __builtin_amdgcn_mfma_f32_16x16x32_bf16(a, b, c, 0, 0, 0);
}

// ---------------------------------------------------------- K0: fused prep
// blocks [0,1024): x->bf16 | [1024,2048): W transposes | [2048,2560): Beff
__global__ __launch_bounds__(256) void k_prep(
    const float* __restrict__ x,
    const float* __restrict__ Wq, const float* __restrict__ Wk,
    const float* __restrict__ Wv, const float* __restrict__ Wo,
    const float* __restrict__ W1,
    u16t* __restrict__ xb, u16t* __restrict__ WT, float* __restrict__ Beff)
{
    __shared__ float smf[1088];   // union: tile[32][33] (trans) | wm[2][256] (eff)
    int bidx = blockIdx.x;
    int t = threadIdx.x;
    if (bidx < 1024) {
        int idx = (bidx * 256 + t) * 4;
        float4 v = *(const float4*)(x + idx);
        u16t* o = xb + idx;
        o[0] = f2b(v.x); o[1] = f2b(v.y); o[2] = f2b(v.z); o[3] = f2b(v.w);
    } else if (bidx < 2048) {
        int t2 = bidx - 1024;
        int z = t2 >> 8, rem = t2 & 255;
        int n0 = (rem & 15) * 32, k0 = (rem >> 4) * 32;
        const float* W = z == 0 ? Wq : z == 1 ? Wk : z == 2 ? Wv : Wo;
        u16t* WTz = WT + (size_t)z * D_SZ * D_SZ;
        float (*tile)[33] = (float(*)[33])smf;
        int r = t >> 3, c4 = (t & 7) * 4;
        float4 v = *(const float4*)(W + (size_t)(k0 + r) * D_SZ + n0 + c4);
        tile[r][c4] = v.x; tile[r][c4 + 1] = v.y; tile[r][c4 + 2] = v.z; tile[r][c4 + 3] = v.w;
        __syncthreads();
        u16t o[4];
        o[0] = f2b(tile[c4][r]); o[1] = f2b(tile[c4 + 1][r]);
        o[2] = f2b(tile[c4 + 2][r]); o[3] = f2b(tile[c4 + 3][r]);
        *(ushort4*)(WTz + (size_t)(n0 + r) * D_SZ + k0 + c4) = *(ushort4*)o;
    } else {
        int k = bidx - 2048;   // 0..511
        float* wm0 = smf;
        float* wm1 = smf + 256;
        const float* wrq = Wq + (size_t)k * D_SZ;
        const float* wrk = Wk + (size_t)k * D_SZ;
        wm0[t & 255] = 0.5f * (wrq[t & 255] + wrq[(t & 255) + DH]);
        wm1[t & 255] = 0.5f * (wrk[t & 255] + wrk[(t & 255) + DH]);
        __syncthreads();
        int half = t >> 7, hcol = t & 127;
        const float* wm = half ? wm1 : wm0;
        const float* W1h = W1 + (half ? (size_t)DH * HH : 0);
        float s = 0.f;
        for (int d = 0; d < 256; ++d) s += wm[d] * W1h[(size_t)d * HH + hcol];
        Beff[(size_t)k * 256 + half * 128 + hcol] = s;
    }
}

// ------------------------------------------------------------- GEMM mainloop
// C[BM=128][BN=NF*16] per block (256 thr, 4 waves; wave w owns rows w*32..+32).
// A: [M][K] k-contig (pre-offset to row m0), B: [N][K] k-contig (pre-offset to n0).
#define KP 72  // padded LDS row stride (bf16 elems)

template<int NF>
static __device__ __forceinline__ void gemm_mainloop(
    const u16t* __restrict__ A, int lda, const u16t* __restrict__ B, int ldb,
    int K, int tid, u16t* Als, u16t* Bls, f32x4 acc[2][NF])
{
    const int w = tid >> 6, lane = tid & 63;
    const int lr = lane & 15, kg = lane >> 4;
    for (int k0 = 0; k0 < K; k0 += 64) {
        if (k0) __syncthreads();
        {
            int c = tid & 7, r0 = tid >> 3;
#pragma unroll
            for (int p = 0; p < 4; ++p) {
                int r = r0 + p * 32;
                *(uint4*)(&Als[r * KP + c * 8]) = *(const uint4*)(&A[(size_t)r * lda + k0 + c * 8]);
            }
#pragma unroll
            for (int p = 0; p < NF / 2; ++p) {
                int r = r0 + p * 32;
                *(uint4*)(&Bls[r * KP + c * 8]) = *(const uint4*)(&B[(size_t)r * ldb + k0 + c * 8]);
            }
        }
        __syncthreads();
#pragma unroll
        for (int kk = 0; kk < 2; ++kk) {
            bf16x8 af[2], bfr[NF];
#pragma unroll
            for (int fi = 0; fi < 2; ++fi)
                af[fi] = *(const bf16x8*)(&Als[(w * 32 + fi * 16 + lr) * KP + kk * 32 + kg * 8]);
#pragma unroll
            for (int fj = 0; fj < NF; ++fj)
                bfr[fj] = *(const bf16x8*)(&Bls[(fj * 16 + lr) * KP + kk * 32 + kg * 8]);
#pragma unroll
            for (int fi = 0; fi < 2; ++fi)
#pragma unroll
                for (int fj = 0; fj < NF; ++fj)
                    acc[fi][fj] = mfma16(af[fi], bfr[fj], acc[fi][fj]);
        }
    }
}

// C-frag element (fi,fj,rr): row = m0+w*32+fi*16+kg*4+rr, col = n0+fj*16+lr  [m89-verified]

// ------------------------------------------- K1: fused QKV GEMMs + mask-ac GEMM
// 1D grid, 640 blocks: [0,384) -> qkv (z = bid/128); [384,640) -> ac.
__global__ __launch_bounds__(256) void k_qkvac(
    const u16t* __restrict__ xb, const u16t* __restrict__ WT,
    const float* __restrict__ x, const float* __restrict__ Beff,
    const float* __restrict__ b1,
    u16t* __restrict__ qb, u16t* __restrict__ kb, u16t* __restrict__ vT,
    float* __restrict__ a, float* __restrict__ cc)
{
    __shared__ __align__(16) char sm[27648];
    int bid = blockIdx.x;
    int t = threadIdx.x;
    if (bid < 384) {
        u16t* Als = (u16t*)sm;               // [128][72]
        u16t* Bls = (u16t*)(sm + 18432);     // [64][72]
        int z = bid / 128, rem = bid & 127;
        int m0 = (rem >> 3) * 128, n0 = (rem & 7) * 64;
        const u16t* A = xb + (size_t)m0 * D_SZ;
        const u16t* Bt = WT + (size_t)z * D_SZ * D_SZ + (size_t)n0 * D_SZ;
        f32x4 acc[2][4] = {};
        gemm_mainloop<4>(A, D_SZ, Bt, D_SZ, D_SZ, t, Als, Bls, acc);
        int w = t >> 6, lane = t & 63, lr = lane & 15, kg = lane >> 4;
        __syncthreads();
        if (z < 2) {
            // stage 128x64 tile in LDS, coalesced store (scale qb by 1/16)
            u16t (*vls)[68] = (u16t(*)[68])Als;
            float scale = z == 0 ? 0.0625f : 1.0f;
#pragma unroll
            for (int fi = 0; fi < 2; ++fi)
#pragma unroll
                for (int fj = 0; fj < 4; ++fj)
#pragma unroll
                    for (int rr = 0; rr < 4; ++rr)
                        vls[w * 32 + fi * 16 + kg * 4 + rr][fj * 16 + lr]
                            = f2b(acc[fi][fj][rr] * scale);
            __syncthreads();
            u16t* dst = z == 0 ? qb : kb;
            int c8 = (t & 7) * 8, r0 = t >> 3;
#pragma unroll
            for (int p = 0; p < 4; ++p) {
                int r = r0 + p * 32;
                *(uint4*)(dst + (size_t)(m0 + r) * D_SZ + n0 + c8) = *(const uint4*)(&vls[r][c8]);
            }
        } else {
            // transpose to vT, coalesced s-contiguous runs
            u16t (*vls)[136] = (u16t(*)[136])Als;   // 64*136*2 = 17408
#pragma unroll
            for (int fi = 0; fi < 2; ++fi)
#pragma unroll
                for (int fj = 0; fj < 4; ++fj)
#pragma unroll
                    for (int rr = 0; rr < 4; ++rr)
                        vls[fj * 16 + lr][w * 32 + fi * 16 + kg * 4 + rr] = f2b(acc[fi][fj][rr]);
            __syncthreads();
            int b = m0 >> 10, s0 = m0 & 1023;
            int cr = t >> 2, seg = t & 3;
            const u16t* srcp = &vls[cr][seg * 32];
            u16t* dstp = vT + (((size_t)(b * D_SZ + n0 + cr)) << 10) + s0 + seg * 32;
#pragma unroll
            for (int qq = 0; qq < 4; ++qq)
                *(uint4*)(dstp + qq * 8) = *(const uint4*)(srcp + qq * 8);
        }
    } else {
        // [a|c] = x @ Beff (f32), a gets +b1. 64 rows x 32 cols, 4x2/thread.
        float (*xs)[68] = (float(*)[68])sm;            // 64x68
        float (*bsT)[68] = (float(*)[68])(sm + 17408); // 32x68 [n][k]
        int t2 = bid - 384;
        int r0 = (t2 & 31) * 64, n0 = (t2 >> 5) * 32;
        int ti = t >> 4, tj = t & 15;
        float acc[4][2] = {};
        for (int k0 = 0; k0 < 512; k0 += 64) {
            if (k0) __syncthreads();
#pragma unroll
            for (int p = 0; p < 4; ++p) {
                int idx = t + p * 256;
                int r = idx >> 4, c4 = (idx & 15) * 4;
                *(float4*)&xs[r][c4] = *(const float4*)(x + (size_t)(r0 + r) * D_SZ + k0 + c4);
            }
#pragma unroll
            for (int p = 0; p < 2; ++p) {
                int idx = t + p * 256;
                int k = idx >> 3, n4 = (idx & 7) * 4;
                float4 v = *(const float4*)(Beff + (size_t)(k0 + k) * 256 + n0 + n4);
                bsT[n4][k] = v.x; bsT[n4 + 1][k] = v.y; bsT[n4 + 2][k] = v.z; bsT[n4 + 3][k] = v.w;
            }
            __syncthreads();
#pragma unroll
            for (int kk = 0; kk < 16; ++kk) {
                float4 xv[4], bv[2];
#pragma unroll
                for (int ri = 0; ri < 4; ++ri) xv[ri] = *(const float4*)&xs[ti + 16 * ri][kk * 4];
#pragma unroll
                for (int rj = 0; rj < 2; ++rj) bv[rj] = *(const float4*)&bsT[tj + 16 * rj][kk * 4];
#pragma unroll
                for (int ri = 0; ri < 4; ++ri)
#pragma unroll
                    for (int rj = 0; rj < 2; ++rj)
                        acc[ri][rj] += xv[ri].x * bv[rj].x + xv[ri].y * bv[rj].y
                                     + xv[ri].z * bv[rj].z + xv[ri].w * bv[rj].w;
            }
        }
        bool isA = n0 < 128;
#pragma unroll
        for (int rj = 0; rj < 2; ++rj) {
            int col = n0 + tj + 16 * rj;
            float badd = isA ? b1[col] : 0.f;
#pragma unroll
            for (int ri = 0; ri < 4; ++ri) {
                int row = r0 + ti + 16 * ri;
                if (isA) a[(size_t)row * HH + col] = acc[ri][rj] + badd;
                else     cc[(size_t)row * HH + (col - 128)] = acc[ri][rj];
            }
        }
    }
}

// ------------------------------------------------------------- K3: mask bits
// 64x64 (i,j) tile per block, 4x4 per thread (strided i=ti+16ri, j=tj+16rj).
// a already has b1 folded in; b2 folded into acc init.
__global__ __launch_bounds__(256) void k_mask(
    const float* __restrict__ a, const float* __restrict__ c,
    const float* __restrict__ W2, const float* __restrict__ b2,
    unsigned char* __restrict__ maskb)
{
    __shared__ __align__(16) float at[64][132];
    __shared__ __align__(16) float ct[64][132];
    __shared__ __align__(16) float w2s[128];
    int b = blockIdx.z, i0 = blockIdx.y * 64, j0 = blockIdx.x * 64;
    int t = threadIdx.x;
    if (t < 128) w2s[t] = W2[t];
#pragma unroll
    for (int p = 0; p < 8; ++p) {
        int idx = t + p * 256;               // 0..2047
        int r = idx >> 5, c4 = (idx & 31) * 4;
        *(float4*)&at[r][c4] = *(const float4*)(a + ((size_t)(b * S_SZ + i0 + r)) * HH + c4);
        *(float4*)&ct[r][c4] = *(const float4*)(c + ((size_t)(b * S_SZ + j0 + r)) * HH + c4);
    }
    __syncthreads();
    float fb2 = b2[0];
    int ti = t >> 4, tj = t & 15;
    float acc[4][4];
#pragma unroll
    for (int ri = 0; ri < 4; ++ri)
#pragma unroll
        for (int rj = 0; rj < 4; ++rj) acc[ri][rj] = fb2;
#pragma unroll 2
    for (int h4 = 0; h4 < 32; ++h4) {
        float4 av[4], cv[4];
        float4 wv = ((const float4*)w2s)[h4];
#pragma unroll
        for (int ri = 0; ri < 4; ++ri) av[ri] = *(const float4*)&at[ti + 16 * ri][h4 * 4];
#pragma unroll
        for (int rj = 0; rj < 4; ++rj) cv[rj] = *(const float4*)&ct[tj + 16 * rj][h4 * 4];
#pragma unroll
        for (int ri = 0; ri < 4; ++ri)
#pragma unroll
            for (int rj = 0; rj < 4; ++rj) {
                acc[ri][rj] += fmaxf(av[ri].x + cv[rj].x, 0.f) * wv.x;
                acc[ri][rj] += fmaxf(av[ri].y + cv[rj].y, 0.f) * wv.y;
                acc[ri][rj] += fmaxf(av[ri].z + cv[rj].z, 0.f) * wv.z;
                acc[ri][rj] += fmaxf(av[ri].w + cv[rj].w, 0.f) * wv.w;
            }
    }
#pragma unroll
    for (int ri = 0; ri < 4; ++ri)
#pragma unroll
        for (int rj = 0; rj < 4; ++rj) {
            int i = i0 + ti + 16 * ri, j = j0 + tj + 16 * rj;
            maskb[((size_t)b << 20) + ((size_t)i << 10) + j] = acc[ri][rj] > 0.f ? 1 : 0;
        }
}

// ---------------------------- K4: P_unnorm = exp(masked QK^T) + row-sum partials
// qb pre-scaled by 1/16. No max-subtraction (|s| ~ O(1)); masked -> 0.
// lpart[(jb*4+bh)][i] = sum over this block's 64 j of exp(s).
__global__ __launch_bounds__(256) void k_scores(
    const u16t* __restrict__ qb, const u16t* __restrict__ kb,
    const unsigned char* __restrict__ maskb, u16t* __restrict__ P,
    float* __restrict__ lpart)
{
    __shared__ u16t Als[128 * KP];
    __shared__ u16t Bls[64 * KP];
    int bh = blockIdx.z, b = bh >> 1, h = bh & 1;
    int jb = blockIdx.x;
    int m0 = blockIdx.y * 128, n0 = jb * 64;
    const u16t* A = qb + (size_t)b * S_SZ * D_SZ + (size_t)m0 * D_SZ + h * DH;
    const u16t* Bt = kb + (size_t)b * S_SZ * D_SZ + (size_t)n0 * D_SZ + h * DH;
    f32x4 acc[2][4] = {};
    gemm_mainloop<4>(A, D_SZ, Bt, D_SZ, DH, threadIdx.x, Als, Bls, acc);
    int w = threadIdx.x >> 6, lane = threadIdx.x & 63, lr = lane & 15, kg = lane >> 4;
    // exp + mask + per-row partial sums
#pragma unroll
    for (int fi = 0; fi < 2; ++fi)
#pragma unroll
        for (int rr = 0; rr < 4; ++rr) {
            int i = m0 + w * 32 + fi * 16 + kg * 4 + rr;
            float rs = 0.f;
#pragma unroll
            for (int fj = 0; fj < 4; ++fj) {
                int j = n0 + fj * 16 + lr;
                bool msk = maskb[((size_t)b << 20) + ((size_t)i << 10) + j] != 0;
                float e = msk ? __expf(acc[fi][fj][rr]) : 0.f;
                acc[fi][fj][rr] = e;
                rs += e;
            }
            rs += __shfl_xor(rs, 1); rs += __shfl_xor(rs, 2);
            rs += __shfl_xor(rs, 4); rs += __shfl_xor(rs, 8);
            if (lr == 0) lpart[((size_t)(jb * 4 + bh) << 10) + i] = rs;
        }
    // stage + coalesced store
    __syncthreads();
    u16t (*vls)[68] = (u16t(*)[68])Als;
#pragma unroll
    for (int fi = 0; fi < 2; ++fi)
#pragma unroll
        for (int fj = 0; fj < 4; ++fj)
#pragma unroll
            for (int rr = 0; rr < 4; ++rr)
                vls[w * 32 + fi * 16 + kg * 4 + rr][fj * 16 + lr] = f2b(acc[fi][fj][rr]);
    __syncthreads();
    int c8 = (threadIdx.x & 7) * 8, r0 = threadIdx.x >> 3;
#pragma unroll
    for (int p = 0; p < 4; ++p) {
        int r = r0 + p * 32;
        *(uint4*)(P + ((size_t)bh << 20) + ((size_t)(m0 + r) << 10) + n0 + c8)
            = *(const uint4*)(&vls[r][c8]);
    }
}

// ------------------------------------------------- K5: PV (+ diag(1/l) epilogue)
__global__ __launch_bounds__(256) void k_pv(
    const u16t* __restrict__ P, const u16t* __restrict__ vT,
    const float* __restrict__ lpart, u16t* __restrict__ ao)
{
    __shared__ u16t Als[128 * KP];
    __shared__ u16t Bls[32 * KP];
    __shared__ float invl[128];
    int bh = blockIdx.z, b = bh >> 1, h = bh & 1;
    int m0 = blockIdx.y * 128, n0 = blockIdx.x * 32;
    int t = threadIdx.x;
    if (t < 128) {   // fixed-order row-sum over 16 j-block partials (deterministic)
        float l = 0.f;
        for (int jb = 0; jb < 16; ++jb)
            l += lpart[((size_t)(jb * 4 + bh) << 10) + m0 + t];
        invl[t] = l > 0.f ? 1.0f / l : 0.f;
    }
    const u16t* A = P + ((size_t)bh << 20) + (size_t)m0 * S_SZ;
    const u16t* Bt = vT + ((size_t)(b * D_SZ + h * DH + n0)) * S_SZ;
    f32x4 acc[2][2] = {};
    gemm_mainloop<2>(A, S_SZ, Bt, S_SZ, S_SZ, t, Als, Bls, acc);
    int w = t >> 6, lane = t & 63, lr = lane & 15, kg = lane >> 4;
    __syncthreads();
    u16t (*ols)[40] = (u16t(*)[40])Als;   // 128x40 u16 = 10240B
#pragma unroll
    for (int fi = 0; fi < 2; ++fi) {
        int rl = w * 32 + fi * 16 + kg * 4;
#pragma unroll
        for (int fj = 0; fj < 2; ++fj)
#pragma unroll
            for (int rr = 0; rr < 4; ++rr)
                ols[rl + rr][fj * 16 + lr] = f2b(acc[fi][fj][rr] * invl[rl + rr]);
    }
    __syncthreads();
    int c8 = (t & 3) * 8, r0 = t >> 2;
#pragma unroll
    for (int p = 0; p < 2; ++p) {
        int r = r0 + p * 64;
        *(uint4*)(ao + ((size_t)(b * S_SZ + m0 + r)) * D_SZ + h * DH + n0 + c8)
            = *(const uint4*)(&ols[r][c8]);
    }
}

// ------------------------------------------------------------ K6: out = ao@Wo+bo
__global__ __launch_bounds__(256) void k_out(
    const u16t* __restrict__ ao, const u16t* __restrict__ WoT,
    const float* __restrict__ bo, float* __restrict__ out)
{
    __shared__ u16t Als[128 * KP];
    __shared__ u16t Bls[32 * KP];
    int m0 = blockIdx.y * 128, n0 = blockIdx.x * 32;
    const u16t* A = ao + (size_t)m0 * D_SZ;
    const u16t* Bt = WoT + (size_t)n0 * D_SZ;
    f32x4 acc[2][2] = {};
    gemm_mainloop<2>(A, D_SZ, Bt, D_SZ, D_SZ, threadIdx.x, Als, Bls, acc);
    int w = threadIdx.x >> 6, lane = threadIdx.x & 63, lr = lane & 15, kg = lane >> 4;
    __syncthreads();
    float (*ols)[36] = (float(*)[36])Als;   // 128x36 f32 = 18432B
#pragma unroll
    for (int fi = 0; fi < 2; ++fi)
#pragma unroll
        for (int fj = 0; fj < 2; ++fj)
#pragma unroll
            for (int rr = 0; rr < 4; ++rr) {
                int rl = w * 32 + fi * 16 + kg * 4 + rr;
                ols[rl][fj * 16 + lr] = acc[fi][fj][rr] + bo[n0 + fj * 16 + lr];
            }
    __syncthreads();
    int c4 = (threadIdx.x & 7) * 4, r0 = threadIdx.x >> 3;
#pragma unroll
    for (int p = 0; p < 4; ++p) {
        int r = r0 + p * 32;
        *(float4*)(out + (size_t)(m0 + r) * D_SZ + n0 + c4) = *(const float4*)(&ols[r][c4]);
    }
}

// ---------------------------------------------------------------------- host
extern "C" void kernel_launch(void* const* d_in, const int* in_sizes, int n_in,
                              void* d_out, int out_size, void* d_ws, size_t ws_size,
                              hipStream_t stream)
{
    const float* x  = (const float*)d_in[0];
    const float* Wq = (const float*)d_in[1];
    const float* Wk = (const float*)d_in[2];
    const float* Wv = (const float*)d_in[3];
    const float* Wo = (const float*)d_in[4];
    const float* bo = (const float*)d_in[5];
    const float* W1 = (const float*)d_in[6];
    const float* b1 = (const float*)d_in[7];
    const float* W2 = (const float*)d_in[8];
    const float* b2 = (const float*)d_in[9];
    float* out = (float*)d_out;

    // workspace carve (all 256B-aligned)
    char* ws = (char*)d_ws;
    size_t off = 0;
    auto carve = [&](size_t bytes) { void* p = ws + off; off += (bytes + 255) & ~(size_t)255; return p; };
    u16t* xb   = (u16t*)carve((size_t)2048 * 512 * 2);
    u16t* WT   = (u16t*)carve((size_t)4 * 512 * 512 * 2);
    u16t* qb   = (u16t*)carve((size_t)2048 * 512 * 2);
    u16t* kb   = (u16t*)carve((size_t)2048 * 512 * 2);
    u16t* vT   = (u16t*)carve((size_t)2 * 512 * 1024 * 2);
    float* Beff = (float*)carve((size_t)512 * 256 * 4);
    float* a   = (float*)carve((size_t)2048 * 128 * 4);
    float* c   = (float*)carve((size_t)2048 * 128 * 4);
    unsigned char* maskb = (unsigned char*)carve((size_t)2 * 1024 * 1024);
    u16t* P    = (u16t*)carve((size_t)4 * 1024 * 1024 * 2);
    float* lpart = (float*)carve((size_t)16 * 4 * 1024 * 4);
    u16t* ao   = (u16t*)carve((size_t)2048 * 512 * 2);
    (void)ws_size;

    k_prep<<<dim3(2560), dim3(256), 0, stream>>>(x, Wq, Wk, Wv, Wo, W1, xb, WT, Beff);
    k_qkvac<<<dim3(640), dim3(256), 0, stream>>>(xb, WT, x, Beff, b1, qb, kb, vT, a, c);
    k_mask<<<dim3(16, 16, 2), dim3(256), 0, stream>>>(a, c, W2, b2, maskb);
    k_scores<<<dim3(16, 8, 4), dim3(256), 0, stream>>>(qb, kb, maskb, P, lpart);
    k_pv<<<dim3(8, 8, 4), dim3(256), 0, stream>>>(P, vT, lpart, ao);
    k_out<<<dim3(16, 16), dim3(256), 0, stream>>>(ao, WT + (size_t)3 * 512 * 512, bo, out);
}

// Round 6
// 110.160 us; speedup vs baseline: 2.9861x; 1.0188x over previous
//
#include <hip/hip_runtime.h>

// AdaptiveSparsityAttention on MI355X (gfx950).
// f32 in/out, internal bf16 MFMA for attention; mask logits in pure f32 via
// algebraic fusion:  a = x @ (0.5*(Wq[:,:256]+Wq[:,256:]) @ W1[:256]) + b1.
//
// R6: all bf16 GEMM staging -> async global_load_lds (16B, direct-to-LDS,
//     linear [r][64] LDS, no pad). Reg-staged path deleted (m93->m97 lever).
//     LDS/block: 24KB (NF=4) / 20KB (NF=2). m97-style frag-read bank
//     conflicts accepted (T2 swizzle is null at 2-phase per regime gate).
// 6 launches: prep, qkvac, mask, scores, pv, out.

typedef unsigned short u16t;
typedef __bf16 bf16x8 __attribute__((ext_vector_type(8)));
typedef float f32x4 __attribute__((ext_vector_type(4)));

#define B_SZ 2
#define S_SZ 1024
#define D_SZ 512
#define DH 256
#define HH 128   // hidden dim of sparsity predictor

static __device__ __forceinline__ u16t f2b(float f) {
    unsigned int u = __builtin_bit_cast(unsigned int, f);
    u += 0x7FFFu + ((u >> 16) & 1u);
    return (u16t)(u >> 16);
}

static __device__ __forceinline__ f32x4 mfma16(bf16x8 a, bf16x8 b, f32x4 c) {
    return __builtin_amdgcn_mfma_f32_16x16x32_bf16(a, b, c, 0, 0, 0);
}

static __device__ __forceinline__ void gload16(const void* g, void* l) {
    __builtin_amdgcn_global_load_lds(
        (const __attribute__((address_space(1))) void*)g,
        (__attribute__((address_space(3))) void*)l, 16, 0, 0);
}

// ---------------------------------------------------------- K0: fused prep
// blocks [0,1024): x->bf16 | [1024,2048): W transposes | [2048,2560): Beff
__global__ __launch_bounds__(256) void k_prep(
    const float* __restrict__ x,
    const float* __restrict__ Wq, const float* __restrict__ Wk,
    const float* __restrict__ Wv, const float* __restrict__ Wo,
    const float* __restrict__ W1,
    u16t* __restrict__ xb, u16t* __restrict__ WT, float* __restrict__ Beff)
{
    __shared__ float smf[1088];   // union: tile[32][33] (trans) | wm[2][256] (eff)
    int bidx = blockIdx.x;
    int t = threadIdx.x;
    if (bidx < 1024) {
        int idx = (bidx * 256 + t) * 4;
        float4 v = *(const float4*)(x + idx);
        u16t* o = xb + idx;
        o[0] = f2b(v.x); o[1] = f2b(v.y); o[2] = f2b(v.z); o[3] = f2b(v.w);
    } else if (bidx < 2048) {
        int t2 = bidx - 1024;
        int z = t2 >> 8, rem = t2 & 255;
        int n0 = (rem & 15) * 32, k0 = (rem >> 4) * 32;
        const float* W = z == 0 ? Wq : z == 1 ? Wk : z == 2 ? Wv : Wo;
        u16t* WTz = WT + (size_t)z * D_SZ * D_SZ;
        float (*tile)[33] = (float(*)[33])smf;
        int r = t >> 3, c4 = (t & 7) * 4;
        float4 v = *(const float4*)(W + (size_t)(k0 + r) * D_SZ + n0 + c4);
        tile[r][c4] = v.x; tile[r][c4 + 1] = v.y; tile[r][c4 + 2] = v.z; tile[r][c4 + 3] = v.w;
        __syncthreads();
        u16t o[4];
        o[0] = f2b(tile[c4][r]); o[1] = f2b(tile[c4 + 1][r]);
        o[2] = f2b(tile[c4 + 2][r]); o[3] = f2b(tile[c4 + 3][r]);
        *(ushort4*)(WTz + (size_t)(n0 + r) * D_SZ + k0 + c4) = *(ushort4*)o;
    } else {
        int k = bidx - 2048;   // 0..511
        float* wm0 = smf;
        float* wm1 = smf + 256;
        const float* wrq = Wq + (size_t)k * D_SZ;
        const float* wrk = Wk + (size_t)k * D_SZ;
        wm0[t & 255] = 0.5f * (wrq[t & 255] + wrq[(t & 255) + DH]);
        wm1[t & 255] = 0.5f * (wrk[t & 255] + wrk[(t & 255) + DH]);
        __syncthreads();
        int half = t >> 7, hcol = t & 127;
        const float* wm = half ? wm1 : wm0;
        const float* W1h = W1 + (half ? (size_t)DH * HH : 0);
        float s = 0.f;
        for (int d = 0; d < 256; ++d) s += wm[d] * W1h[(size_t)d * HH + hcol];
        Beff[(size_t)k * 256 + half * 128 + hcol] = s;
    }
}

// ------------------------------------------------------------- GEMM mainloop
// C[BM=128][BN=NF*16] per block (256 thr, 4 waves; wave w owns rows w*32..+32).
// A: [M][K] k-contig (pre-offset to row m0), B: [N][K] k-contig (pre-offset to n0).
// LDS: linear Als[128][64], Bls[NF*16][64] u16. Staged via global_load_lds:
// each instr writes 1KB = 8 rows x 128B; lane l -> row base+(l>>3), 16B col (l&7).
template<int NF>
static __device__ __forceinline__ void gemm_mainloop(
    const u16t* __restrict__ A, int lda, const u16t* __restrict__ B, int ldb,
    int K, int tid, u16t* Als, u16t* Bls, f32x4 acc[2][NF])
{
    const int w = tid >> 6, lane = tid & 63;
    const int lr = lane & 15, kg = lane >> 4;
    const int srow = lane >> 3, scol = (lane & 7) * 8;
    for (int k0 = 0; k0 < K; k0 += 64) {
        if (k0) __syncthreads();
#pragma unroll
        for (int q = 0; q < 4; ++q) {
            int ci = w * 4 + q;                 // 0..15 -> rows ci*8..+8
            gload16(A + (size_t)(ci * 8 + srow) * lda + k0 + scol, Als + ci * 512);
        }
#pragma unroll
        for (int q = 0; q < NF / 2; ++q) {
            int cj = w * (NF / 2) + q;          // rows cj*8..+8
            gload16(B + (size_t)(cj * 8 + srow) * ldb + k0 + scol, Bls + cj * 512);
        }
        __syncthreads();
#pragma unroll
        for (int kk = 0; kk < 2; ++kk) {
            bf16x8 af[2], bfr[NF];
#pragma unroll
            for (int fi = 0; fi < 2; ++fi)
                af[fi] = *(const bf16x8*)(&Als[(w * 32 + fi * 16 + lr) * 64 + kk * 32 + kg * 8]);
#pragma unroll
            for (int fj = 0; fj < NF; ++fj)
                bfr[fj] = *(const bf16x8*)(&Bls[(fj * 16 + lr) * 64 + kk * 32 + kg * 8]);
#pragma unroll
            for (int fi = 0; fi < 2; ++fi)
#pragma unroll
                for (int fj = 0; fj < NF; ++fj)
                    acc[fi][fj] = mfma16(af[fi], bfr[fj], acc[fi][fj]);
        }
    }
}

// C-frag element (fi,fj,rr): row = m0+w*32+fi*16+kg*4+rr, col = n0+fj*16+lr  [m89-verified]

// ------------------------------------------- K1: fused QKV GEMMs + mask-ac GEMM
// 1D grid, 640 blocks: [0,384) -> qkv (z = bid/128); [384,640) -> ac.
__global__ __launch_bounds__(256) void k_qkvac(
    const u16t* __restrict__ xb, const u16t* __restrict__ WT,
    const float* __restrict__ x, const float* __restrict__ Beff,
    const float* __restrict__ b1,
    u16t* __restrict__ qb, u16t* __restrict__ kb, u16t* __restrict__ vT,
    float* __restrict__ a, float* __restrict__ cc)
{
    __shared__ __align__(16) char sm[27648];
    int bid = blockIdx.x;
    int t = threadIdx.x;
    if (bid < 384) {
        u16t* Als = (u16t*)sm;               // [128][64] = 16KB
        u16t* Bls = Als + 8192;              // [64][64]  = 8KB
        int z = bid / 128, rem = bid & 127;
        int m0 = (rem >> 3) * 128, n0 = (rem & 7) * 64;
        const u16t* A = xb + (size_t)m0 * D_SZ;
        const u16t* Bt = WT + (size_t)z * D_SZ * D_SZ + (size_t)n0 * D_SZ;
        f32x4 acc[2][4] = {};
        gemm_mainloop<4>(A, D_SZ, Bt, D_SZ, D_SZ, t, Als, Bls, acc);
        int w = t >> 6, lane = t & 63, lr = lane & 15, kg = lane >> 4;
        __syncthreads();
        if (z < 2) {
            // stage 128x64 tile in LDS, coalesced store (scale qb by 1/16)
            u16t (*vls)[68] = (u16t(*)[68])sm;
            float scale = z == 0 ? 0.0625f : 1.0f;
#pragma unroll
            for (int fi = 0; fi < 2; ++fi)
#pragma unroll
                for (int fj = 0; fj < 4; ++fj)
#pragma unroll
                    for (int rr = 0; rr < 4; ++rr)
                        vls[w * 32 + fi * 16 + kg * 4 + rr][fj * 16 + lr]
                            = f2b(acc[fi][fj][rr] * scale);
            __syncthreads();
            u16t* dst = z == 0 ? qb : kb;
            int c8 = (t & 7) * 8, r0 = t >> 3;
#pragma unroll
            for (int p = 0; p < 4; ++p) {
                int r = r0 + p * 32;
                *(uint4*)(dst + (size_t)(m0 + r) * D_SZ + n0 + c8) = *(const uint4*)(&vls[r][c8]);
            }
        } else {
            // transpose to vT, coalesced s-contiguous runs
            u16t (*vls)[136] = (u16t(*)[136])sm;   // 64*136*2 = 17408
#pragma unroll
            for (int fi = 0; fi < 2; ++fi)
#pragma unroll
                for (int fj = 0; fj < 4; ++fj)
#pragma unroll
                    for (int rr = 0; rr < 4; ++rr)
                        vls[fj * 16 + lr][w * 32 + fi * 16 + kg * 4 + rr] = f2b(acc[fi][fj][rr]);
            __syncthreads();
            int b = m0 >> 10, s0 = m0 & 1023;
            int cr = t >> 2, seg = t & 3;
            const u16t* srcp = &vls[cr][seg * 32];
            u16t* dstp = vT + (((size_t)(b * D_SZ + n0 + cr)) << 10) + s0 + seg * 32;
#pragma unroll
            for (int qq = 0; qq < 4; ++qq)
                *(uint4*)(dstp + qq * 8) = *(const uint4*)(srcp + qq * 8);
        }
    } else {
        // [a|c] = x @ Beff (f32), a gets +b1. 64 rows x 32 cols, 4x2/thread.
        float (*xs)[68] = (float(*)[68])sm;            // 64x68
        float (*bsT)[68] = (float(*)[68])(sm + 17408); // 32x68 [n][k]
        int t2 = bid - 384;
        int r0 = (t2 & 31) * 64, n0 = (t2 >> 5) * 32;
        int ti = t >> 4, tj = t & 15;
        float acc[4][2] = {};
        for (int k0 = 0; k0 < 512; k0 += 64) {
            if (k0) __syncthreads();
#pragma unroll
            for (int p = 0; p < 4; ++p) {
                int idx = t + p * 256;
                int r = idx >> 4, c4 = (idx & 15) * 4;
                *(float4*)&xs[r][c4] = *(const float4*)(x + (size_t)(r0 + r) * D_SZ + k0 + c4);
            }
#pragma unroll
            for (int p = 0; p < 2; ++p) {
                int idx = t + p * 256;
                int k = idx >> 3, n4 = (idx & 7) * 4;
                float4 v = *(const float4*)(Beff + (size_t)(k0 + k) * 256 + n0 + n4);
                bsT[n4][k] = v.x; bsT[n4 + 1][k] = v.y; bsT[n4 + 2][k] = v.z; bsT[n4 + 3][k] = v.w;
            }
            __syncthreads();
#pragma unroll
            for (int kk = 0; kk < 16; ++kk) {
                float4 xv[4], bv[2];
#pragma unroll
                for (int ri = 0; ri < 4; ++ri) xv[ri] = *(const float4*)&xs[ti + 16 * ri][kk * 4];
#pragma unroll
                for (int rj = 0; rj < 2; ++rj) bv[rj] = *(const float4*)&bsT[tj + 16 * rj][kk * 4];
#pragma unroll
                for (int ri = 0; ri < 4; ++ri)
#pragma unroll
                    for (int rj = 0; rj < 2; ++rj)
                        acc[ri][rj] += xv[ri].x * bv[rj].x + xv[ri].y * bv[rj].y
                                     + xv[ri].z * bv[rj].z + xv[ri].w * bv[rj].w;
            }
        }
        bool isA = n0 < 128;
#pragma unroll
        for (int rj = 0; rj < 2; ++rj) {
            int col = n0 + tj + 16 * rj;
            float badd = isA ? b1[col] : 0.f;
#pragma unroll
            for (int ri = 0; ri < 4; ++ri) {
                int row = r0 + ti + 16 * ri;
                if (isA) a[(size_t)row * HH + col] = acc[ri][rj] + badd;
                else     cc[(size_t)row * HH + (col - 128)] = acc[ri][rj];
            }
        }
    }
}

// ------------------------------------------------------------- K3: mask bits
// 64x64 (i,j) tile per block, 4x4 per thread (strided i=ti+16ri, j=tj+16rj).
// a already has b1 folded in; b2 folded into acc init.
__global__ __launch_bounds__(256) void k_mask(
    const float* __restrict__ a, const float* __restrict__ c,
    const float* __restrict__ W2, const float* __restrict__ b2,
    unsigned char* __restrict__ maskb)
{
    __shared__ __align__(16) float at[64][132];
    __shared__ __align__(16) float ct[64][132];
    __shared__ __align__(16) float w2s[128];
    int b = blockIdx.z, i0 = blockIdx.y * 64, j0 = blockIdx.x * 64;
    int t = threadIdx.x;
    if (t < 128) w2s[t] = W2[t];
#pragma unroll
    for (int p = 0; p < 8; ++p) {
        int idx = t + p * 256;               // 0..2047
        int r = idx >> 5, c4 = (idx & 31) * 4;
        *(float4*)&at[r][c4] = *(const float4*)(a + ((size_t)(b * S_SZ + i0 + r)) * HH + c4);
        *(float4*)&ct[r][c4] = *(const float4*)(c + ((size_t)(b * S_SZ + j0 + r)) * HH + c4);
    }
    __syncthreads();
    float fb2 = b2[0];
    int ti = t >> 4, tj = t & 15;
    float acc[4][4];
#pragma unroll
    for (int ri = 0; ri < 4; ++ri)
#pragma unroll
        for (int rj = 0; rj < 4; ++rj) acc[ri][rj] = fb2;
#pragma unroll 2
    for (int h4 = 0; h4 < 32; ++h4) {
        float4 av[4], cv[4];
        float4 wv = ((const float4*)w2s)[h4];
#pragma unroll
        for (int ri = 0; ri < 4; ++ri) av[ri] = *(const float4*)&at[ti + 16 * ri][h4 * 4];
#pragma unroll
        for (int rj = 0; rj < 4; ++rj) cv[rj] = *(const float4*)&ct[tj + 16 * rj][h4 * 4];
#pragma unroll
        for (int ri = 0; ri < 4; ++ri)
#pragma unroll
            for (int rj = 0; rj < 4; ++rj) {
                acc[ri][rj] += fmaxf(av[ri].x + cv[rj].x, 0.f) * wv.x;
                acc[ri][rj] += fmaxf(av[ri].y + cv[rj].y, 0.f) * wv.y;
                acc[ri][rj] += fmaxf(av[ri].z + cv[rj].z, 0.f) * wv.z;
                acc[ri][rj] += fmaxf(av[ri].w + cv[rj].w, 0.f) * wv.w;
            }
    }
#pragma unroll
    for (int ri = 0; ri < 4; ++ri)
#pragma unroll
        for (int rj = 0; rj < 4; ++rj) {
            int i = i0 + ti + 16 * ri, j = j0 + tj + 16 * rj;
            maskb[((size_t)b << 20) + ((size_t)i << 10) + j] = acc[ri][rj] > 0.f ? 1 : 0;
        }
}

// ---------------------------- K4: P_unnorm = exp(masked QK^T) + row-sum partials
// qb pre-scaled by 1/16. No max-subtraction (|s| ~ O(1)); masked -> 0.
// lpart[(jb*4+bh)][i] = sum over this block's 64 j of exp(s).
__global__ __launch_bounds__(256) void k_scores(
    const u16t* __restrict__ qb, const u16t* __restrict__ kb,
    const unsigned char* __restrict__ maskb, u16t* __restrict__ P,
    float* __restrict__ lpart)
{
    __shared__ __align__(16) u16t sm[12288];   // Als 16KB + Bls 8KB
    u16t* Als = sm;
    u16t* Bls = sm + 8192;
    int bh = blockIdx.z, b = bh >> 1, h = bh & 1;
    int jb = blockIdx.x;
    int m0 = blockIdx.y * 128, n0 = jb * 64;
    const u16t* A = qb + (size_t)b * S_SZ * D_SZ + (size_t)m0 * D_SZ + h * DH;
    const u16t* Bt = kb + (size_t)b * S_SZ * D_SZ + (size_t)n0 * D_SZ + h * DH;
    f32x4 acc[2][4] = {};
    gemm_mainloop<4>(A, D_SZ, Bt, D_SZ, DH, threadIdx.x, Als, Bls, acc);
    int w = threadIdx.x >> 6, lane = threadIdx.x & 63, lr = lane & 15, kg = lane >> 4;
    // exp + mask + per-row partial sums
#pragma unroll
    for (int fi = 0; fi < 2; ++fi)
#pragma unroll
        for (int rr = 0; rr < 4; ++rr) {
            int i = m0 + w * 32 + fi * 16 + kg * 4 + rr;
            float rs = 0.f;
#pragma unroll
            for (int fj = 0; fj < 4; ++fj) {
                int j = n0 + fj * 16 + lr;
                bool msk = maskb[((size_t)b << 20) + ((size_t)i << 10) + j] != 0;
                float e = msk ? __expf(acc[fi][fj][rr]) : 0.f;
                acc[fi][fj][rr] = e;
                rs += e;
            }
            rs += __shfl_xor(rs, 1); rs += __shfl_xor(rs, 2);
            rs += __shfl_xor(rs, 4); rs += __shfl_xor(rs, 8);
            if (lr == 0) lpart[((size_t)(jb * 4 + bh) << 10) + i] = rs;
        }
    // stage + coalesced store
    __syncthreads();
    u16t (*vls)[68] = (u16t(*)[68])sm;
#pragma unroll
    for (int fi = 0; fi < 2; ++fi)
#pragma unroll
        for (int fj = 0; fj < 4; ++fj)
#pragma unroll
            for (int rr = 0; rr < 4; ++rr)
                vls[w * 32 + fi * 16 + kg * 4 + rr][fj * 16 + lr] = f2b(acc[fi][fj][rr]);
    __syncthreads();
    int c8 = (threadIdx.x & 7) * 8, r0 = threadIdx.x >> 3;
#pragma unroll
    for (int p = 0; p < 4; ++p) {
        int r = r0 + p * 32;
        *(uint4*)(P + ((size_t)bh << 20) + ((size_t)(m0 + r) << 10) + n0 + c8)
            = *(const uint4*)(&vls[r][c8]);
    }
}

// ------------------------------------------------- K5: PV (+ diag(1/l) epilogue)
__global__ __launch_bounds__(256) void k_pv(
    const u16t* __restrict__ P, const u16t* __restrict__ vT,
    const float* __restrict__ lpart, u16t* __restrict__ ao)
{
    __shared__ __align__(16) u16t sm[10240];   // Als 16KB + Bls 4KB
    __shared__ float invl[128];
    u16t* Als = sm;
    u16t* Bls = sm + 8192;
    int bh = blockIdx.z, b = bh >> 1, h = bh & 1;
    int m0 = blockIdx.y * 128, n0 = blockIdx.x * 32;
    int t = threadIdx.x;
    if (t < 128) {   // fixed-order row-sum over 16 j-block partials (deterministic)
        float l = 0.f;
        for (int jb = 0; jb < 16; ++jb)
            l += lpart[((size_t)(jb * 4 + bh) << 10) + m0 + t];
        invl[t] = l > 0.f ? 1.0f / l : 0.f;
    }
    const u16t* A = P + ((size_t)bh << 20) + (size_t)m0 * S_SZ;
    const u16t* Bt = vT + ((size_t)(b * D_SZ + h * DH + n0)) * S_SZ;
    f32x4 acc[2][2] = {};
    gemm_mainloop<2>(A, S_SZ, Bt, S_SZ, S_SZ, t, Als, Bls, acc);
    int w = t >> 6, lane = t & 63, lr = lane & 15, kg = lane >> 4;
    __syncthreads();
    u16t (*ols)[40] = (u16t(*)[40])sm;   // 128x40 u16 = 10240B
#pragma unroll
    for (int fi = 0; fi < 2; ++fi) {
        int rl = w * 32 + fi * 16 + kg * 4;
#pragma unroll
        for (int fj = 0; fj < 2; ++fj)
#pragma unroll
            for (int rr = 0; rr < 4; ++rr)
                ols[rl + rr][fj * 16 + lr] = f2b(acc[fi][fj][rr] * invl[rl + rr]);
    }
    __syncthreads();
    int c8 = (t & 3) * 8, r0 = t >> 2;
#pragma unroll
    for (int p = 0; p < 2; ++p) {
        int r = r0 + p * 64;
        *(uint4*)(ao + ((size_t)(b * S_SZ + m0 + r)) * D_SZ + h * DH + n0 + c8)
            = *(const uint4*)(&ols[r][c8]);
    }
}

// ------------------------------------------------------------ K6: out = ao@Wo+bo
__global__ __launch_bounds__(256) void k_out(
    const u16t* __restrict__ ao, const u16t* __restrict__ WoT,
    const float* __restrict__ bo, float* __restrict__ out)
{
    __shared__ __align__(16) u16t sm[10240];   // Als 16KB + Bls 4KB = 20KB
    u16t* Als = sm;
    u16t* Bls = sm + 8192;
    int m0 = blockIdx.y * 128, n0 = blockIdx.x * 32;
    const u16t* A = ao + (size_t)m0 * D_SZ;
    const u16t* Bt = WoT + (size_t)n0 * D_SZ;
    f32x4 acc[2][2] = {};
    gemm_mainloop<2>(A, D_SZ, Bt, D_SZ, D_SZ, threadIdx.x, Als, Bls, acc);
    int w = threadIdx.x >> 6, lane = threadIdx.x & 63, lr = lane & 15, kg = lane >> 4;
    __syncthreads();
    float (*ols)[36] = (float(*)[36])sm;   // 128x36 f32 = 18432B <= 20480B
#pragma unroll
    for (int fi = 0; fi < 2; ++fi)
#pragma unroll
        for (int fj = 0; fj < 2; ++fj)
#pragma unroll
            for (int rr = 0; rr < 4; ++rr) {
                int rl = w * 32 + fi * 16 + kg * 4 + rr;
                ols[rl][fj * 16 + lr] = acc[fi][fj][rr] + bo[n0 + fj * 16 + lr];
            }
    __syncthreads();
    int c4 = (threadIdx.x & 7) * 4, r0 = threadIdx.x >> 3;
#pragma unroll
    for (int p = 0; p < 4; ++p) {
        int r = r0 + p * 32;
        *(float4*)(out + (size_t)(m0 + r) * D_SZ + n0 + c4) = *(const float4*)(&ols[r][c4]);
    }
}

// ---------------------------------------------------------------------- host
extern "C" void kernel_launch(void* const* d_in, const int* in_sizes, int n_in,
                              void* d_out, int out_size, void* d_ws, size_t ws_size,
                              hipStream_t stream)
{
    const float* x  = (const float*)d_in[0];
    const float* Wq = (const float*)d_in[1];
    const float* Wk = (const float*)d_in[2];
    const float* Wv = (const float*)d_in[3];
    const float* Wo = (const float*)d_in[4];
    const float* bo = (const float*)d_in[5];
    const float* W1 = (const float*)d_in[6];
    const float* b1 = (const float*)d_in[7];
    const float* W2 = (const float*)d_in[8];
    const float* b2 = (const float*)d_in[9];
    float* out = (float*)d_out;

    // workspace carve (all 256B-aligned)
    char* ws = (char*)d_ws;
    size_t off = 0;
    auto carve = [&](size_t bytes) { void* p = ws + off; off += (bytes + 255) & ~(size_t)255; return p; };
    u16t* xb   = (u16t*)carve((size_t)2048 * 512 * 2);
    u16t* WT   = (u16t*)carve((size_t)4 * 512 * 512 * 2);
    u16t* qb   = (u16t*)carve((size_t)2048 * 512 * 2);
    u16t* kb   = (u16t*)carve((size_t)2048 * 512 * 2);
    u16t* vT   = (u16t*)carve((size_t)2 * 512 * 1024 * 2);
    float* Beff = (float*)carve((size_t)512 * 256 * 4);
    float* a   = (float*)carve((size_t)2048 * 128 * 4);
    float* c   = (float*)carve((size_t)2048 * 128 * 4);
    unsigned char* maskb = (unsigned char*)carve((size_t)2 * 1024 * 1024);
    u16t* P    = (u16t*)carve((size_t)4 * 1024 * 1024 * 2);
    float* lpart = (float*)carve((size_t)16 * 4 * 1024 * 4);
    u16t* ao   = (u16t*)carve((size_t)2048 * 512 * 2);
    (void)ws_size;

    k_prep<<<dim3(2560), dim3(256), 0, stream>>>(x, Wq, Wk, Wv, Wo, W1, xb, WT, Beff);
    k_qkvac<<<dim3(640), dim3(256), 0, stream>>>(xb, WT, x, Beff, b1, qb, kb, vT, a, c);
    k_mask<<<dim3(16, 16, 2), dim3(256), 0, stream>>>(a, c, W2, b2, maskb);
    k_scores<<<dim3(16, 8, 4), dim3(256), 0, stream>>>(qb, kb, maskb, P, lpart);
    k_pv<<<dim3(8, 8, 4), dim3(256), 0, stream>>>(P, vT, lpart, ao);
    k_out<<<dim3(16, 16), dim3(256), 0, stream>>>(ao, WT + (size_t)3 * 512 * 512, bo, out);
}